// Round 1
// 482.979 us; speedup vs baseline: 1.0362x; 1.0362x over previous
//
#include <hip/hip_runtime.h>
#include <cstdint>
#include <cstddef>

#define B_ 2
#define S_ 2048
#define D_ 1024
#define H_ 16
#define DH_ 64
#define FF_ 4096
#define M_ (B_*S_)
#define MB_ ((size_t)1 << 20)
#define NT_ (S_/64)

using u16 = unsigned short;
using short8 = __attribute__((ext_vector_type(8))) short;
using short4v = __attribute__((ext_vector_type(4))) short;
using floatx4 = __attribute__((ext_vector_type(4))) float;

__device__ __forceinline__ float bf2f(u16 u) {
    return __uint_as_float(((uint32_t)u) << 16);
}
__device__ __forceinline__ u16 f2bf(float f) {
    uint32_t u = __float_as_uint(f);
    u += 0x7fffu + ((u >> 16) & 1u);   // RNE
    return (u16)(u >> 16);
}
// pack two f32 -> bf16x2 in one VALU op (RNE). Non-volatile: scheduler-friendly.
__device__ __forceinline__ uint32_t cvtpk_bf16(float lo, float hi) {
    uint32_t r;
    asm("v_cvt_pk_bf16_f32 %0, %1, %2" : "=v"(r) : "v"(lo), "v"(hi));
    return r;
}
// async global->LDS, 16B per lane; LDS dest = wave-uniform base + lane*16
__device__ __forceinline__ void async_copy16(const u16* g, u16* l) {
    __builtin_amdgcn_global_load_lds(
        (const __attribute__((address_space(1))) uint32_t*)g,
        (__attribute__((address_space(3))) uint32_t*)l, 16, 0, 0);
}

// ---------------------------------------------------------------------------
// f32 -> bf16 elementwise convert (x). n multiple of 1024.
// ---------------------------------------------------------------------------
__global__ __launch_bounds__(256) void cvt_f32_bf16(
    const float* __restrict__ in, u16* __restrict__ out, int n)
{
    const int i = (blockIdx.x * 256 + threadIdx.x) * 4;
    if (i < n) {
        const float4 v = *(const float4*)(in + i);
        out[i + 0] = f2bf(v.x);
        out[i + 1] = f2bf(v.y);
        out[i + 2] = f2bf(v.z);
        out[i + 3] = f2bf(v.w);
    }
}

// ---------------------------------------------------------------------------
// mask (int32) -> additive bias: 0 or -1e30 (log2-domain compatible)
// ---------------------------------------------------------------------------
__global__ __launch_bounds__(256) void mask_bias(
    const int* __restrict__ mask, float* __restrict__ bias, int n)
{
    const int i = blockIdx.x * 256 + threadIdx.x;
    if (i < n) bias[i] = mask[i] ? 0.f : -1e30f;
}

// ---------------------------------------------------------------------------
// transpose+convert: in f32 (R x C) -> out bf16 (C x R)
// ---------------------------------------------------------------------------
__global__ void transpose_cvt(const float* __restrict__ in, u16* __restrict__ out,
                              int R, int C) {
    __shared__ float t[32][33];
    const int bx = blockIdx.x * 32, by = blockIdx.y * 32;
    const int tx = threadIdx.x, ty = threadIdx.y;
#pragma unroll
    for (int i = 0; i < 32; i += 8)
        t[ty + i][tx] = in[(size_t)(by + ty + i) * C + bx + tx];
    __syncthreads();
#pragma unroll
    for (int i = 0; i < 32; i += 8)
        out[(size_t)(bx + ty + i) * R + by + tx] = f2bf(t[tx][ty + i]);
}

// Fused transpose of the four D x D weights (WQ,WK,WV -> Wqkvt; WY -> WYt).
__global__ void transpose_cvt4(
    const float* __restrict__ WQ, const float* __restrict__ WK,
    const float* __restrict__ WV, const float* __restrict__ WY,
    u16* __restrict__ Wqkvt, u16* __restrict__ WYt)
{
    __shared__ float t[32][33];
    const int zz = blockIdx.z;
    const float* in = zz == 0 ? WQ : zz == 1 ? WK : zz == 2 ? WV : WY;
    u16* out = zz < 3 ? Wqkvt + (size_t)zz * D_ * D_ : WYt;
    const int bx = blockIdx.x * 32, by = blockIdx.y * 32;
    const int tx = threadIdx.x, ty = threadIdx.y;
#pragma unroll
    for (int i = 0; i < 32; i += 8)
        t[ty + i][tx] = in[(size_t)(by + ty + i) * D_ + bx + tx];
    __syncthreads();
#pragma unroll
    for (int i = 0; i < 32; i += 8)
        out[(size_t)(bx + ty + i) * D_ + by + tx] = f2bf(t[tx][ty + i]);
}

// ---------------------------------------------------------------------------
// Generic GEMM: C(MxN) = A(MxK) @ W + bias; W as Wt (NxK bf16), bias f32.
// 128x128 tile, BK=32, 4 waves, mfma 16x16x32 bf16.
// ---------------------------------------------------------------------------
template<bool GELU, bool OUT_F32>
__global__ __launch_bounds__(256) void gemm_bt(
    const u16* __restrict__ A, const u16* __restrict__ Bt,
    const float* __restrict__ bias, void* __restrict__ Cout,
    int M, int N, int K)
{
    __shared__ alignas(16) u16 As[128 * 32];
    __shared__ alignas(16) u16 Bs[128 * 32];
    const int tid = threadIdx.x;
    const int w = tid >> 6, lane = tid & 63;
    const int lm = lane & 15, quad = lane >> 4;
    const int wm = w >> 1, wn = w & 1;
    const size_t m0 = (size_t)blockIdx.y * 128, n0 = (size_t)blockIdx.x * 128;

    const int rowS = w * 16 + (lane >> 2);
    const int colS = (lane & 3) * 8;
    const u16* gA = A + (m0 + rowS) * K + colS;
    const u16* gB = Bt + (n0 + rowS) * K + colS;
    u16* lA = As + w * 512;
    u16* lB = Bs + w * 512;

    floatx4 acc[4][4];
    const floatx4 z = {0.f, 0.f, 0.f, 0.f};
#pragma unroll
    for (int i = 0; i < 4; ++i)
#pragma unroll
        for (int j = 0; j < 4; ++j) acc[i][j] = z;

    for (int k0 = 0; k0 < K; k0 += 32) {
        __syncthreads();
        async_copy16(gA, lA);
        async_copy16(gA + (size_t)64 * K, lA + 2048);
        async_copy16(gB, lB);
        async_copy16(gB + (size_t)64 * K, lB + 2048);
        gA += 32; gB += 32;
        __syncthreads();

        short8 af[4], bfr[4];
#pragma unroll
        for (int t = 0; t < 4; ++t)
            af[t] = *(const short8*)&As[(wm * 64 + t * 16 + lm) * 32 + quad * 8];
#pragma unroll
        for (int t = 0; t < 4; ++t)
            bfr[t] = *(const short8*)&Bs[(wn * 64 + t * 16 + lm) * 32 + quad * 8];
#pragma unroll
        for (int i = 0; i < 4; ++i)
#pragma unroll
            for (int j = 0; j < 4; ++j)
                acc[i][j] = __builtin_amdgcn_mfma_f32_16x16x32_bf16(
                    af[i], bfr[j], acc[i][j], 0, 0, 0);
    }

#pragma unroll
    for (int i = 0; i < 4; ++i) {
        const size_t r0 = m0 + wm * 64 + i * 16 + quad * 4;
#pragma unroll
        for (int j = 0; j < 4; ++j) {
            const size_t c = n0 + wn * 64 + j * 16 + lm;
            const float bv = bias[c];
#pragma unroll
            for (int t = 0; t < 4; ++t) {
                float v = acc[i][j][t] + bv;
                if (GELU) v = 0.5f * v * (1.f + erff(v * 0.70710678118f));
                if (OUT_F32) ((float*)Cout)[(r0 + t) * (size_t)N + c] = v;
                else         ((u16*)Cout)[(r0 + t) * (size_t)N + c] = f2bf(v);
            }
        }
    }
}

// ---------------------------------------------------------------------------
// Split-K=2 GEMM: two K-halves (blockIdx.z) atomically accumulate f32 into
// a zeroed Cout; k-half 0 adds bias. Doubles blocks/CU for narrow-N GEMMs
// (N=1024: 256 -> 512 blocks) where 1 block/CU serializes the barrier drain.
// ---------------------------------------------------------------------------
__global__ __launch_bounds__(256) void gemm_bt_sk2(
    const u16* __restrict__ A, const u16* __restrict__ Bt,
    const float* __restrict__ bias, float* __restrict__ Cout,
    int M, int N, int K)
{
    __shared__ alignas(16) u16 As[128 * 32];
    __shared__ alignas(16) u16 Bs[128 * 32];
    const int tid = threadIdx.x;
    const int w = tid >> 6, lane = tid & 63;
    const int lm = lane & 15, quad = lane >> 4;
    const int wm = w >> 1, wn = w & 1;
    const int kh = blockIdx.z;
    const int Ks = K >> 1;
    const size_t m0 = (size_t)blockIdx.y * 128, n0 = (size_t)blockIdx.x * 128;

    const int rowS = w * 16 + (lane >> 2);
    const int colS = (lane & 3) * 8;
    const u16* gA = A + (m0 + rowS) * K + (size_t)kh * Ks + colS;
    const u16* gB = Bt + (n0 + rowS) * K + (size_t)kh * Ks + colS;
    u16* lA = As + w * 512;
    u16* lB = Bs + w * 512;

    floatx4 acc[4][4];
    const floatx4 z = {0.f, 0.f, 0.f, 0.f};
#pragma unroll
    for (int i = 0; i < 4; ++i)
#pragma unroll
        for (int j = 0; j < 4; ++j) acc[i][j] = z;

    for (int k0 = 0; k0 < Ks; k0 += 32) {
        __syncthreads();
        async_copy16(gA, lA);
        async_copy16(gA + (size_t)64 * K, lA + 2048);
        async_copy16(gB, lB);
        async_copy16(gB + (size_t)64 * K, lB + 2048);
        gA += 32; gB += 32;
        __syncthreads();

        short8 af[4], bfr[4];
#pragma unroll
        for (int t = 0; t < 4; ++t)
            af[t] = *(const short8*)&As[(wm * 64 + t * 16 + lm) * 32 + quad * 8];
#pragma unroll
        for (int t = 0; t < 4; ++t)
            bfr[t] = *(const short8*)&Bs[(wn * 64 + t * 16 + lm) * 32 + quad * 8];
#pragma unroll
        for (int i = 0; i < 4; ++i)
#pragma unroll
            for (int j = 0; j < 4; ++j)
                acc[i][j] = __builtin_amdgcn_mfma_f32_16x16x32_bf16(
                    af[i], bfr[j], acc[i][j], 0, 0, 0);
    }

#pragma unroll
    for (int i = 0; i < 4; ++i) {
        const size_t r0 = m0 + wm * 64 + i * 16 + quad * 4;
#pragma unroll
        for (int j = 0; j < 4; ++j) {
            const size_t c = n0 + wn * 64 + j * 16 + lm;
            const float bv = (kh == 0) ? bias[c] : 0.f;
#pragma unroll
            for (int t = 0; t < 4; ++t)
                atomicAdd(&Cout[(r0 + t) * (size_t)N + c], acc[i][j][t] + bv);
        }
    }
}

// ---------------------------------------------------------------------------
// Fused QKV GEMM: A(M x 1024) @ Wqkv (1024 x 3072), Wqkvt rows: [WQ^T;WK^T;WV^T].
// Q,K written [m][1024]; V written transposed per head: Vt[((b*16+h)*64+dh)*S + s].
// ---------------------------------------------------------------------------
__global__ __launch_bounds__(256) void gemm_qkv(
    const u16* __restrict__ A, const u16* __restrict__ Bt,
    const float* __restrict__ bQ, const float* __restrict__ bK,
    const float* __restrict__ bV,
    u16* __restrict__ Qb, u16* __restrict__ Kb, u16* __restrict__ Vt)
{
    const int K = D_, N = 3 * D_;
    __shared__ alignas(16) u16 As[128 * 32];
    __shared__ alignas(16) u16 Bs[128 * 32];
    const int tid = threadIdx.x;
    const int w = tid >> 6, lane = tid & 63;
    const int lm = lane & 15, quad = lane >> 4;
    const int wm = w >> 1, wn = w & 1;
    const size_t m0 = (size_t)blockIdx.y * 128, n0 = (size_t)blockIdx.x * 128;

    const int rowS = w * 16 + (lane >> 2);
    const int colS = (lane & 3) * 8;
    const u16* gA = A + (m0 + rowS) * K + colS;
    const u16* gB = Bt + (n0 + rowS) * K + colS;
    u16* lA = As + w * 512;
    u16* lB = Bs + w * 512;

    floatx4 acc[4][4];
    const floatx4 z = {0.f, 0.f, 0.f, 0.f};
#pragma unroll
    for (int i = 0; i < 4; ++i)
#pragma unroll
        for (int j = 0; j < 4; ++j) acc[i][j] = z;

    for (int k0 = 0; k0 < K; k0 += 32) {
        __syncthreads();
        async_copy16(gA, lA);
        async_copy16(gA + (size_t)64 * K, lA + 2048);
        async_copy16(gB, lB);
        async_copy16(gB + (size_t)64 * K, lB + 2048);
        gA += 32; gB += 32;
        __syncthreads();

        short8 af[4], bfr[4];
#pragma unroll
        for (int t = 0; t < 4; ++t)
            af[t] = *(const short8*)&As[(wm * 64 + t * 16 + lm) * 32 + quad * 8];
#pragma unroll
        for (int t = 0; t < 4; ++t)
            bfr[t] = *(const short8*)&Bs[(wn * 64 + t * 16 + lm) * 32 + quad * 8];
#pragma unroll
        for (int i = 0; i < 4; ++i)
#pragma unroll
            for (int j = 0; j < 4; ++j)
                acc[i][j] = __builtin_amdgcn_mfma_f32_16x16x32_bf16(
                    af[i], bfr[j], acc[i][j], 0, 0, 0);
    }

#pragma unroll
    for (int i = 0; i < 4; ++i) {
        const size_t r0 = m0 + wm * 64 + i * 16 + quad * 4;
#pragma unroll
        for (int j = 0; j < 4; ++j) {
            const size_t c = n0 + wn * 64 + j * 16 + lm;
            const int sel = (int)(c >> 10);       // 0=Q 1=K 2=V (uniform per j)
            const int col = (int)(c & 1023);
            const float bv = sel == 0 ? bQ[col] : (sel == 1 ? bK[col] : bV[col]);
#pragma unroll
            for (int t = 0; t < 4; ++t) {
                const size_t r = r0 + t;
                const u16 v = f2bf(acc[i][j][t] + bv);
                if (sel == 0)      Qb[r * (size_t)D_ + col] = v;
                else if (sel == 1) Kb[r * (size_t)D_ + col] = v;
                else {
                    const int h = col >> 6, dh = col & 63;
                    const int bb = (int)(r >> 11), s = (int)(r & 2047);
                    Vt[((size_t)((bb * 16 + h) * 64 + dh)) * S_ + s] = v;
                }
            }
        }
    }
}

// ---------------------------------------------------------------------------
// Flash attention, S^T formulation: grid (S/64, B*H); 4 waves x 16 queries.
// VALU-diet version: exp2-domain softmax (scale = 0.125*log2e folded into the
// score FMA), v_cvt_pk_bf16_f32 for P/output conversion, defer-max rescale
// (THR=8 in log2 units -> P bounded by 2^8), double-buffered K/V LDS with a
// single barrier per tile and next-tile global loads issued under compute.
// ---------------------------------------------------------------------------
__global__ __launch_bounds__(256) void attn_kernel(
    const u16* __restrict__ Q, const u16* __restrict__ Kg,
    const u16* __restrict__ Vt, const float* __restrict__ mbias,
    u16* __restrict__ O)
{
    __shared__ alignas(16) u16 Kt[2][64 * 72];
    __shared__ alignas(16) u16 Vs[2][64 * 72];   // [dh][key]
    const int tid = threadIdx.x, w = tid >> 6, lane = tid & 63;
    const int lm = lane & 15, quad = lane >> 4;
    const int b = blockIdx.y >> 4, h = blockIdx.y & 15;
    const int q0 = blockIdx.x * 64;

    // Q B-frag: n = lane&15 -> query, k = quad*8+j -> dh
    const u16* qp = Q + ((size_t)(b * S_ + q0 + w * 16 + lm)) * D_ + h * 64;
    const short8 bq0 = *(const short8*)(qp + quad * 8);
    const short8 bq1 = *(const short8*)(qp + 32 + quad * 8);

    // staging: thread covers row tid>>2 (0..63), 16 u16 at col (tid&3)*16
    const int sRow = tid >> 2, sCol = (tid & 3) * 16;
    const u16* gK = Kg + ((size_t)(b * S_ + sRow)) * D_ + h * 64 + sCol;
    const u16* gV = Vt + ((size_t)((b * 16 + h) * 64 + sRow)) * S_ + sCol;

    float mrow = -1e30f, lrow = 0.f;
    floatx4 o[4];                                // o[dhs][reg], O^T layout
    const floatx4 z = {0.f, 0.f, 0.f, 0.f};
#pragma unroll
    for (int i = 0; i < 4; ++i) o[i] = z;

    const float* bp = mbias + b * S_;
    const float SCL = 0.18033688011112042f;      // 0.125 * log2(e)

    // prologue: tile 0 into registers
    short8 rk0 = *(const short8*)(gK);
    short8 rk1 = *(const short8*)(gK + 8);
    short8 rv0 = *(const short8*)(gV);
    short8 rv1 = *(const short8*)(gV + 8);

    for (int it = 0; it < NT_; ++it) {
        u16* kb = Kt[it & 1];
        u16* vb = Vs[it & 1];
        *(short8*)&kb[sRow * 72 + sCol]     = rk0;
        *(short8*)&kb[sRow * 72 + sCol + 8] = rk1;
        *(short8*)&vb[sRow * 72 + sCol]     = rv0;
        *(short8*)&vb[sRow * 72 + sCol + 8] = rv1;
        __syncthreads();
        if (it + 1 < NT_) {                      // issue next tile under compute
            gK += (size_t)64 * D_; gV += 64;
            rk0 = *(const short8*)(gK);
            rk1 = *(const short8*)(gK + 8);
            rv0 = *(const short8*)(gV);
            rv1 = *(const short8*)(gV + 8);
        }

        // S^T (64 keys x 16 queries): A = K-frag, B = Q-frag
        floatx4 st[4];
        __builtin_amdgcn_s_setprio(1);
#pragma unroll
        for (int ks = 0; ks < 4; ++ks) {
            floatx4 s = z;
            const short8 ak0 = *(const short8*)&kb[(ks * 16 + lm) * 72 + quad * 8];
            const short8 ak1 = *(const short8*)&kb[(ks * 16 + lm) * 72 + 32 + quad * 8];
            s = __builtin_amdgcn_mfma_f32_16x16x32_bf16(ak0, bq0, s, 0, 0, 0);
            s = __builtin_amdgcn_mfma_f32_16x16x32_bf16(ak1, bq1, s, 0, 0, 0);
            const float4 mb4 = *(const float4*)&bp[it * 64 + ks * 16 + quad * 4];
            st[ks][0] = fmaf(s[0], SCL, mb4.x);
            st[ks][1] = fmaf(s[1], SCL, mb4.y);
            st[ks][2] = fmaf(s[2], SCL, mb4.z);
            st[ks][3] = fmaf(s[3], SCL, mb4.w);
        }
        __builtin_amdgcn_s_setprio(0);

        // tile max: max3-friendly triples, then cross-quad (xor 16, 32)
        float t0 = fmaxf(fmaxf(st[0][0], st[0][1]), st[0][2]);
        float t1 = fmaxf(fmaxf(st[0][3], st[1][0]), st[1][1]);
        float t2 = fmaxf(fmaxf(st[1][2], st[1][3]), st[2][0]);
        float t3 = fmaxf(fmaxf(st[2][1], st[2][2]), st[2][3]);
        float t4 = fmaxf(fmaxf(st[3][0], st[3][1]), st[3][2]);
        float tm = fmaxf(fmaxf(t0, t1), t2);
        tm = fmaxf(fmaxf(tm, t3), t4);
        tm = fmaxf(tm, st[3][3]);
        tm = fmaxf(tm, __shfl_xor(tm, 16));
        tm = fmaxf(tm, __shfl_xor(tm, 32));

        // defer-max: only rescale when the running max grew by > 8 (log2)
        if (!__all(tm <= mrow + 8.f)) {
            const float mn = fmaxf(mrow, tm);
            const float al = __builtin_amdgcn_exp2f(mrow - mn);
            mrow = mn;
            lrow *= al;
#pragma unroll
            for (int d = 0; d < 4; ++d) o[d] *= al;
        }

        float rs = 0.f;
#pragma unroll
        for (int ks = 0; ks < 4; ++ks)
#pragma unroll
            for (int r = 0; r < 4; ++r) {
                const float p = __builtin_amdgcn_exp2f(st[ks][r] - mrow);
                st[ks][r] = p; rs += p;
            }
        rs += __shfl_xor(rs, 16);
        rs += __shfl_xor(rs, 32);
        lrow += rs;

        // P^T B-frags for 16x16x16: k = quad*4+j (key), n = lm (query)
        short4v pb[4];
#pragma unroll
        for (int ks = 0; ks < 4; ++ks) {
            uint2 uu;
            uu.x = cvtpk_bf16(st[ks][0], st[ks][1]);
            uu.y = cvtpk_bf16(st[ks][2], st[ks][3]);
            pb[ks] = __builtin_bit_cast(short4v, uu);
        }
        // O^T += V^T · P^T ; V^T A-frag: m=dh (lm), k=key=quad*4+j (b64 read)
        __builtin_amdgcn_s_setprio(1);
#pragma unroll
        for (int d = 0; d < 4; ++d)
#pragma unroll
            for (int ks = 0; ks < 4; ++ks) {
                const short4v av = *(const short4v*)&vb[(d * 16 + lm) * 72 + ks * 16 + quad * 4];
                o[d] = __builtin_amdgcn_mfma_f32_16x16x16bf16_1k(av, pb[ks], o[d], 0, 0, 0);
            }
        __builtin_amdgcn_s_setprio(0);
    }
    // O^T C-layout: row=dh=quad*4+reg, col=query=lm -> 4 contiguous u16/store
    const float inv = __builtin_amdgcn_rcpf(lrow);
    u16* op = O + ((size_t)(b * S_ + q0 + w * 16 + lm)) * D_ + h * 64 + quad * 4;
#pragma unroll
    for (int d = 0; d < 4; ++d) {
        uint2 uu;
        uu.x = cvtpk_bf16(o[d][0] * inv, o[d][1] * inv);
        uu.y = cvtpk_bf16(o[d][2] * inv, o[d][3] * inv);
        *(uint2*)(op + d * 16) = uu;
    }
}

// ---------------------------------------------------------------------------
// out = LayerNorm(mainp + resid) * gamma + beta. gamma/beta f32.
// Safe for out == mainp (rows are block-disjoint; reads precede writes).
// ---------------------------------------------------------------------------
template<bool MAIN_F32, bool RESID_F32, bool OUT_F32>
__global__ __launch_bounds__(256) void add_ln(
    const void* __restrict__ mainp, const void* __restrict__ resid,
    const float* __restrict__ gamma, const float* __restrict__ beta,
    void* __restrict__ out)
{
    const int row = blockIdx.x;
    const size_t base = (size_t)row * D_;
    const int t = threadIdx.x;
    const int w = t >> 6, lane = t & 63;
    float v[4];
#pragma unroll
    for (int i = 0; i < 4; ++i) {
        const int c = i * 256 + t;
        const float mv = MAIN_F32 ? ((const float*)mainp)[base + c]
                                  : bf2f(((const u16*)mainp)[base + c]);
        const float rv = RESID_F32 ? ((const float*)resid)[base + c]
                                   : bf2f(((const u16*)resid)[base + c]);
        v[i] = mv + rv;
    }
    float s = v[0] + v[1] + v[2] + v[3];
#pragma unroll
    for (int off = 32; off >= 1; off >>= 1) s += __shfl_xor(s, off);
    __shared__ float red[8];
    if (lane == 0) red[w] = s;
    __syncthreads();
    const float mean = (red[0] + red[1] + red[2] + red[3]) * (1.0f / D_);
    float q = 0.f;
#pragma unroll
    for (int i = 0; i < 4; ++i) { const float dd = v[i] - mean; q += dd * dd; }
#pragma unroll
    for (int off = 32; off >= 1; off >>= 1) q += __shfl_xor(q, off);
    if (lane == 0) red[4 + w] = q;
    __syncthreads();
    const float var = (red[4] + red[5] + red[6] + red[7]) * (1.0f / D_);
    const float rstd = rsqrtf(var + 1e-5f);
#pragma unroll
    for (int i = 0; i < 4; ++i) {
        const int c = i * 256 + t;
        const float o = (v[i] - mean) * rstd * gamma[c] + beta[c];
        if (OUT_F32) ((float*)out)[base + c] = o;
        else         ((u16*)out)[base + c] = f2bf(o);
    }
}

// ---------------------------------------------------------------------------
extern "C" void kernel_launch(void* const* d_in, const int* in_sizes, int n_in,
                              void* d_out, int out_size, void* d_ws, size_t ws_size,
                              hipStream_t stream)
{
    const float* x   = (const float*)d_in[0];
    const int* mask  = (const int*)d_in[1];
    const float* WQ = (const float*)d_in[2];  const float* bQ = (const float*)d_in[3];
    const float* WK = (const float*)d_in[4];  const float* bK = (const float*)d_in[5];
    const float* WV = (const float*)d_in[6];  const float* bV = (const float*)d_in[7];
    const float* WY = (const float*)d_in[8];  const float* bY = (const float*)d_in[9];
    const float* ln1w = (const float*)d_in[10]; const float* ln1b = (const float*)d_in[11];
    const float* ln2w = (const float*)d_in[12]; const float* ln2b = (const float*)d_in[13];
    const float* W1 = (const float*)d_in[14]; const float* b1 = (const float*)d_in[15];
    const float* W2 = (const float*)d_in[16]; const float* b2 = (const float*)d_in[17];

    // Workspace (peak 48 MB + 16 KB bias):
    //  xb[0,8) -> W1t -> W2t ; Wqkvt[8,14)+WYt[14,16) -> hbf[8,16)
    //  Qb[16,24)+Kb[24,32) -> Ypf32[16,32) -> G[16,48)
    //  Vt[32,40), Yat[40,48) -> G
    char* ws = (char*)d_ws;
    u16* xb    = (u16*)(ws + 0  * MB_);
    u16* Wqkvt = (u16*)(ws + 8  * MB_);        // 6 MB: [WQ^T; WK^T; WV^T]
    u16* WYt   = (u16*)(ws + 14 * MB_);        // 2 MB
    u16* Qb    = (u16*)(ws + 16 * MB_);
    u16* Kb    = (u16*)(ws + 24 * MB_);
    u16* Vt    = (u16*)(ws + 32 * MB_);        // [b][h][dh][s]
    u16* Yat   = (u16*)(ws + 40 * MB_);
    float* Ypf = (float*)(ws + 16 * MB_);      // 16 MB f32, after Qb/Kb dead
    u16* hbf   = (u16*)(ws + 8  * MB_);        // after Wqkvt/WYt dead
    u16* W1t   = (u16*)(ws + 0  * MB_);        // after xb dead
    u16* G     = (u16*)(ws + 16 * MB_);        // after Ypf/Vt/Yat dead
    u16* W2t   = (u16*)(ws + 0  * MB_);        // after W1t dead
    float* mb  = (float*)(ws + 48 * MB_);      // 16 KB mask bias

    const dim3 tb(32, 8);

    cvt_f32_bf16<<<(M_*D_)/1024, 256, 0, stream>>>(x, xb, M_*D_);
    mask_bias<<<(B_*S_)/256, 256, 0, stream>>>(mask, mb, B_*S_);
    transpose_cvt4<<<dim3(D_/32, D_/32, 4), tb, 0, stream>>>(WQ, WK, WV, WY, Wqkvt, WYt);

    gemm_qkv<<<dim3(3*D_/128, M_/128), 256, 0, stream>>>(xb, Wqkvt, bQ, bK, bV, Qb, Kb, Vt);

    attn_kernel<<<dim3(S_/64, B_*H_), 256, 0, stream>>>(Qb, Kb, Vt, mb, Yat);

    // Y-proj: split-K=2 atomic f32 (N=1024 -> 512 blocks instead of 256)
    hipMemsetAsync(Ypf, 0, (size_t)M_ * D_ * 4, stream);
    gemm_bt_sk2<<<dim3(D_/128, M_/128, 2), 256, 0, stream>>>(Yat, WYt, bY, Ypf, M_, D_, D_);

    add_ln<true,true,false><<<M_, 256, 0, stream>>>(Ypf, x, ln1w, ln1b, hbf);

    transpose_cvt<<<dim3(FF_/32, D_/32), tb, 0, stream>>>(W1, W1t, D_, FF_);
    gemm_bt<true,false><<<dim3(FF_/128, M_/128), 256, 0, stream>>>(hbf, W1t, b1, G, M_, FF_, D_);

    transpose_cvt<<<dim3(D_/32, FF_/32), tb, 0, stream>>>(W2, W2t, FF_, D_);
    // FF2: split-K=2 atomic f32 into d_out
    hipMemsetAsync(d_out, 0, (size_t)M_ * D_ * 4, stream);
    gemm_bt_sk2<<<dim3(D_/128, M_/128, 2), 256, 0, stream>>>(G, W2t, b2, (float*)d_out, M_, D_, FF_);

    add_ln<true,false,true><<<M_, 256, 0, stream>>>((float*)d_out, hbf, ln2w, ln2b, d_out);
}

// Round 2
// 458.535 us; speedup vs baseline: 1.0914x; 1.0533x over previous
//
#include <hip/hip_runtime.h>
#include <cstdint>
#include <cstddef>

#define B_ 2
#define S_ 2048
#define D_ 1024
#define H_ 16
#define DH_ 64
#define FF_ 4096
#define M_ (B_*S_)
#define MB_ ((size_t)1 << 20)
#define NT_ (S_/64)

using u16 = unsigned short;
using short8 = __attribute__((ext_vector_type(8))) short;
using short4v = __attribute__((ext_vector_type(4))) short;
using floatx4 = __attribute__((ext_vector_type(4))) float;

__device__ __forceinline__ float bf2f(u16 u) {
    return __uint_as_float(((uint32_t)u) << 16);
}
__device__ __forceinline__ u16 f2bf(float f) {
    uint32_t u = __float_as_uint(f);
    u += 0x7fffu + ((u >> 16) & 1u);   // RNE
    return (u16)(u >> 16);
}
// pack two f32 -> bf16x2 in one VALU op (RNE)
__device__ __forceinline__ uint32_t cvtpk_bf16(float lo, float hi) {
    uint32_t r;
    asm("v_cvt_pk_bf16_f32 %0, %1, %2" : "=v"(r) : "v"(lo), "v"(hi));
    return r;
}
// async global->LDS, 16B per lane; LDS dest = wave-uniform base + lane*16
__device__ __forceinline__ void async_copy16(const u16* g, u16* l) {
    __builtin_amdgcn_global_load_lds(
        (const __attribute__((address_space(1))) uint32_t*)g,
        (__attribute__((address_space(3))) uint32_t*)l, 16, 0, 0);
}

// ---------------------------------------------------------------------------
// f32 -> bf16 elementwise convert (x). n multiple of 1024.
// ---------------------------------------------------------------------------
__global__ __launch_bounds__(256) void cvt_f32_bf16(
    const float* __restrict__ in, u16* __restrict__ out, int n)
{
    const int i = (blockIdx.x * 256 + threadIdx.x) * 4;
    if (i < n) {
        const float4 v = *(const float4*)(in + i);
        out[i + 0] = f2bf(v.x);
        out[i + 1] = f2bf(v.y);
        out[i + 2] = f2bf(v.z);
        out[i + 3] = f2bf(v.w);
    }
}

// ---------------------------------------------------------------------------
// mask (int32) -> additive bias: 0 or -1e30
// ---------------------------------------------------------------------------
__global__ __launch_bounds__(256) void mask_bias(
    const int* __restrict__ mask, float* __restrict__ bias, int n)
{
    const int i = blockIdx.x * 256 + threadIdx.x;
    if (i < n) bias[i] = mask[i] ? 0.f : -1e30f;
}

// ---------------------------------------------------------------------------
// transpose+convert: in f32 (R x C) -> out bf16 (C x R)
// ---------------------------------------------------------------------------
__global__ void transpose_cvt(const float* __restrict__ in, u16* __restrict__ out,
                              int R, int C) {
    __shared__ float t[32][33];
    const int bx = blockIdx.x * 32, by = blockIdx.y * 32;
    const int tx = threadIdx.x, ty = threadIdx.y;
#pragma unroll
    for (int i = 0; i < 32; i += 8)
        t[ty + i][tx] = in[(size_t)(by + ty + i) * C + bx + tx];
    __syncthreads();
#pragma unroll
    for (int i = 0; i < 32; i += 8)
        out[(size_t)(bx + ty + i) * R + by + tx] = f2bf(t[tx][ty + i]);
}

// Fused transpose of the four D x D weights (WQ,WK,WV -> Wqkvt; WY -> WYt).
__global__ void transpose_cvt4(
    const float* __restrict__ WQ, const float* __restrict__ WK,
    const float* __restrict__ WV, const float* __restrict__ WY,
    u16* __restrict__ Wqkvt, u16* __restrict__ WYt)
{
    __shared__ float t[32][33];
    const int zz = blockIdx.z;
    const float* in = zz == 0 ? WQ : zz == 1 ? WK : zz == 2 ? WV : WY;
    u16* out = zz < 3 ? Wqkvt + (size_t)zz * D_ * D_ : WYt;
    const int bx = blockIdx.x * 32, by = blockIdx.y * 32;
    const int tx = threadIdx.x, ty = threadIdx.y;
#pragma unroll
    for (int i = 0; i < 32; i += 8)
        t[ty + i][tx] = in[(size_t)(by + ty + i) * D_ + bx + tx];
    __syncthreads();
#pragma unroll
    for (int i = 0; i < 32; i += 8)
        out[(size_t)(bx + ty + i) * D_ + by + tx] = f2bf(t[tx][ty + i]);
}

// ---------------------------------------------------------------------------
// Generic GEMM: C(MxN) = A(MxK) @ W + bias; W as Wt (NxK bf16), bias f32.
// 128x128 tile, BK=32, 4 waves, mfma 16x16x32 bf16.
// ---------------------------------------------------------------------------
template<bool GELU, bool OUT_F32>
__global__ __launch_bounds__(256) void gemm_bt(
    const u16* __restrict__ A, const u16* __restrict__ Bt,
    const float* __restrict__ bias, void* __restrict__ Cout,
    int M, int N, int K)
{
    __shared__ alignas(16) u16 As[128 * 32];
    __shared__ alignas(16) u16 Bs[128 * 32];
    const int tid = threadIdx.x;
    const int w = tid >> 6, lane = tid & 63;
    const int lm = lane & 15, quad = lane >> 4;
    const int wm = w >> 1, wn = w & 1;
    const size_t m0 = (size_t)blockIdx.y * 128, n0 = (size_t)blockIdx.x * 128;

    const int rowS = w * 16 + (lane >> 2);
    const int colS = (lane & 3) * 8;
    const u16* gA = A + (m0 + rowS) * K + colS;
    const u16* gB = Bt + (n0 + rowS) * K + colS;
    u16* lA = As + w * 512;
    u16* lB = Bs + w * 512;

    floatx4 acc[4][4];
    const floatx4 z = {0.f, 0.f, 0.f, 0.f};
#pragma unroll
    for (int i = 0; i < 4; ++i)
#pragma unroll
        for (int j = 0; j < 4; ++j) acc[i][j] = z;

    for (int k0 = 0; k0 < K; k0 += 32) {
        __syncthreads();
        async_copy16(gA, lA);
        async_copy16(gA + (size_t)64 * K, lA + 2048);
        async_copy16(gB, lB);
        async_copy16(gB + (size_t)64 * K, lB + 2048);
        gA += 32; gB += 32;
        __syncthreads();

        short8 af[4], bfr[4];
#pragma unroll
        for (int t = 0; t < 4; ++t)
            af[t] = *(const short8*)&As[(wm * 64 + t * 16 + lm) * 32 + quad * 8];
#pragma unroll
        for (int t = 0; t < 4; ++t)
            bfr[t] = *(const short8*)&Bs[(wn * 64 + t * 16 + lm) * 32 + quad * 8];
#pragma unroll
        for (int i = 0; i < 4; ++i)
#pragma unroll
            for (int j = 0; j < 4; ++j)
                acc[i][j] = __builtin_amdgcn_mfma_f32_16x16x32_bf16(
                    af[i], bfr[j], acc[i][j], 0, 0, 0);
    }

#pragma unroll
    for (int i = 0; i < 4; ++i) {
        const size_t r0 = m0 + wm * 64 + i * 16 + quad * 4;
#pragma unroll
        for (int j = 0; j < 4; ++j) {
            const size_t c = n0 + wn * 64 + j * 16 + lm;
            const float bv = bias[c];
#pragma unroll
            for (int t = 0; t < 4; ++t) {
                float v = acc[i][j][t] + bv;
                if (GELU) v = 0.5f * v * (1.f + erff(v * 0.70710678118f));
                if (OUT_F32) ((float*)Cout)[(r0 + t) * (size_t)N + c] = v;
                else         ((u16*)Cout)[(r0 + t) * (size_t)N + c] = f2bf(v);
            }
        }
    }
}

// ---------------------------------------------------------------------------
// Split-K GEMM with PARTIAL STORES (no atomics). gridDim.z = nsplit.
// kh==0 writes out0 (+bias); kh>0 writes Pext + (kh-1)*M*N. The next add_ln
// kernel reduces the partials. XCD-chunked blockIdx swizzle for A-panel L2
// locality (valid: nwg per z-plane is a multiple of 8).
// ---------------------------------------------------------------------------
__global__ __launch_bounds__(256) void gemm_bt_skp(
    const u16* __restrict__ A, const u16* __restrict__ Bt,
    const float* __restrict__ bias, float* __restrict__ out0,
    float* __restrict__ Pext, int M, int N, int K)
{
    __shared__ alignas(16) u16 As[128 * 32];
    __shared__ alignas(16) u16 Bs[128 * 32];
    const int tid = threadIdx.x;
    const int w = tid >> 6, lane = tid & 63;
    const int lm = lane & 15, quad = lane >> 4;
    const int wm = w >> 1, wn = w & 1;
    const int kh = blockIdx.z;
    const int Ks = K / gridDim.z;

    // XCD-chunked swizzle: each XCD gets a contiguous chunk of logical tiles
    const int nwg = gridDim.x * gridDim.y;
    int bid = blockIdx.y * gridDim.x + blockIdx.x;
    if ((nwg & 7) == 0) {
        const int cpx = nwg >> 3;
        bid = (bid & 7) * cpx + (bid >> 3);
    }
    const int bx = bid % gridDim.x, by = bid / gridDim.x;
    const size_t m0 = (size_t)by * 128, n0 = (size_t)bx * 128;

    const int rowS = w * 16 + (lane >> 2);
    const int colS = (lane & 3) * 8;
    const u16* gA = A + (m0 + rowS) * K + (size_t)kh * Ks + colS;
    const u16* gB = Bt + (n0 + rowS) * K + (size_t)kh * Ks + colS;
    u16* lA = As + w * 512;
    u16* lB = Bs + w * 512;

    floatx4 acc[4][4];
    const floatx4 z = {0.f, 0.f, 0.f, 0.f};
#pragma unroll
    for (int i = 0; i < 4; ++i)
#pragma unroll
        for (int j = 0; j < 4; ++j) acc[i][j] = z;

    for (int k0 = 0; k0 < Ks; k0 += 32) {
        __syncthreads();
        async_copy16(gA, lA);
        async_copy16(gA + (size_t)64 * K, lA + 2048);
        async_copy16(gB, lB);
        async_copy16(gB + (size_t)64 * K, lB + 2048);
        gA += 32; gB += 32;
        __syncthreads();

        short8 af[4], bfr[4];
#pragma unroll
        for (int t = 0; t < 4; ++t)
            af[t] = *(const short8*)&As[(wm * 64 + t * 16 + lm) * 32 + quad * 8];
#pragma unroll
        for (int t = 0; t < 4; ++t)
            bfr[t] = *(const short8*)&Bs[(wn * 64 + t * 16 + lm) * 32 + quad * 8];
#pragma unroll
        for (int i = 0; i < 4; ++i)
#pragma unroll
            for (int j = 0; j < 4; ++j)
                acc[i][j] = __builtin_amdgcn_mfma_f32_16x16x32_bf16(
                    af[i], bfr[j], acc[i][j], 0, 0, 0);
    }

    float* Cout = (kh == 0) ? out0 : Pext + (size_t)(kh - 1) * ((size_t)M * N);
#pragma unroll
    for (int i = 0; i < 4; ++i) {
        const size_t r0 = m0 + wm * 64 + i * 16 + quad * 4;
#pragma unroll
        for (int j = 0; j < 4; ++j) {
            const size_t c = n0 + wn * 64 + j * 16 + lm;
            const float bv = (kh == 0) ? bias[c] : 0.f;
#pragma unroll
            for (int t = 0; t < 4; ++t)
                Cout[(r0 + t) * (size_t)N + c] = acc[i][j][t] + bv;
        }
    }
}

// ---------------------------------------------------------------------------
// Fallback: split-K=2 GEMM, atomic f32 accumulate (used when ws too small).
// ---------------------------------------------------------------------------
__global__ __launch_bounds__(256) void gemm_bt_sk2(
    const u16* __restrict__ A, const u16* __restrict__ Bt,
    const float* __restrict__ bias, float* __restrict__ Cout,
    int M, int N, int K)
{
    __shared__ alignas(16) u16 As[128 * 32];
    __shared__ alignas(16) u16 Bs[128 * 32];
    const int tid = threadIdx.x;
    const int w = tid >> 6, lane = tid & 63;
    const int lm = lane & 15, quad = lane >> 4;
    const int wm = w >> 1, wn = w & 1;
    const int kh = blockIdx.z;
    const int Ks = K >> 1;
    const size_t m0 = (size_t)blockIdx.y * 128, n0 = (size_t)blockIdx.x * 128;

    const int rowS = w * 16 + (lane >> 2);
    const int colS = (lane & 3) * 8;
    const u16* gA = A + (m0 + rowS) * K + (size_t)kh * Ks + colS;
    const u16* gB = Bt + (n0 + rowS) * K + (size_t)kh * Ks + colS;
    u16* lA = As + w * 512;
    u16* lB = Bs + w * 512;

    floatx4 acc[4][4];
    const floatx4 z = {0.f, 0.f, 0.f, 0.f};
#pragma unroll
    for (int i = 0; i < 4; ++i)
#pragma unroll
        for (int j = 0; j < 4; ++j) acc[i][j] = z;

    for (int k0 = 0; k0 < Ks; k0 += 32) {
        __syncthreads();
        async_copy16(gA, lA);
        async_copy16(gA + (size_t)64 * K, lA + 2048);
        async_copy16(gB, lB);
        async_copy16(gB + (size_t)64 * K, lB + 2048);
        gA += 32; gB += 32;
        __syncthreads();

        short8 af[4], bfr[4];
#pragma unroll
        for (int t = 0; t < 4; ++t)
            af[t] = *(const short8*)&As[(wm * 64 + t * 16 + lm) * 32 + quad * 8];
#pragma unroll
        for (int t = 0; t < 4; ++t)
            bfr[t] = *(const short8*)&Bs[(wn * 64 + t * 16 + lm) * 32 + quad * 8];
#pragma unroll
        for (int i = 0; i < 4; ++i)
#pragma unroll
            for (int j = 0; j < 4; ++j)
                acc[i][j] = __builtin_amdgcn_mfma_f32_16x16x32_bf16(
                    af[i], bfr[j], acc[i][j], 0, 0, 0);
    }

#pragma unroll
    for (int i = 0; i < 4; ++i) {
        const size_t r0 = m0 + wm * 64 + i * 16 + quad * 4;
#pragma unroll
        for (int j = 0; j < 4; ++j) {
            const size_t c = n0 + wn * 64 + j * 16 + lm;
            const float bv = (kh == 0) ? bias[c] : 0.f;
#pragma unroll
            for (int t = 0; t < 4; ++t)
                atomicAdd(&Cout[(r0 + t) * (size_t)N + c], acc[i][j][t] + bv);
        }
    }
}

// ---------------------------------------------------------------------------
// Fused QKV GEMM: A(M x 1024) @ Wqkv (1024 x 3072), Wqkvt rows: [WQ^T;WK^T;WV^T].
// Q,K written [m][1024]; V written transposed per head: Vt[((b*16+h)*64+dh)*S + s].
// ---------------------------------------------------------------------------
__global__ __launch_bounds__(256) void gemm_qkv(
    const u16* __restrict__ A, const u16* __restrict__ Bt,
    const float* __restrict__ bQ, const float* __restrict__ bK,
    const float* __restrict__ bV,
    u16* __restrict__ Qb, u16* __restrict__ Kb, u16* __restrict__ Vt)
{
    const int K = D_, N = 3 * D_;
    __shared__ alignas(16) u16 As[128 * 32];
    __shared__ alignas(16) u16 Bs[128 * 32];
    const int tid = threadIdx.x;
    const int w = tid >> 6, lane = tid & 63;
    const int lm = lane & 15, quad = lane >> 4;
    const int wm = w >> 1, wn = w & 1;
    const size_t m0 = (size_t)blockIdx.y * 128, n0 = (size_t)blockIdx.x * 128;

    const int rowS = w * 16 + (lane >> 2);
    const int colS = (lane & 3) * 8;
    const u16* gA = A + (m0 + rowS) * K + colS;
    const u16* gB = Bt + (n0 + rowS) * K + colS;
    u16* lA = As + w * 512;
    u16* lB = Bs + w * 512;

    floatx4 acc[4][4];
    const floatx4 z = {0.f, 0.f, 0.f, 0.f};
#pragma unroll
    for (int i = 0; i < 4; ++i)
#pragma unroll
        for (int j = 0; j < 4; ++j) acc[i][j] = z;

    for (int k0 = 0; k0 < K; k0 += 32) {
        __syncthreads();
        async_copy16(gA, lA);
        async_copy16(gA + (size_t)64 * K, lA + 2048);
        async_copy16(gB, lB);
        async_copy16(gB + (size_t)64 * K, lB + 2048);
        gA += 32; gB += 32;
        __syncthreads();

        short8 af[4], bfr[4];
#pragma unroll
        for (int t = 0; t < 4; ++t)
            af[t] = *(const short8*)&As[(wm * 64 + t * 16 + lm) * 32 + quad * 8];
#pragma unroll
        for (int t = 0; t < 4; ++t)
            bfr[t] = *(const short8*)&Bs[(wn * 64 + t * 16 + lm) * 32 + quad * 8];
#pragma unroll
        for (int i = 0; i < 4; ++i)
#pragma unroll
            for (int j = 0; j < 4; ++j)
                acc[i][j] = __builtin_amdgcn_mfma_f32_16x16x32_bf16(
                    af[i], bfr[j], acc[i][j], 0, 0, 0);
    }

#pragma unroll
    for (int i = 0; i < 4; ++i) {
        const size_t r0 = m0 + wm * 64 + i * 16 + quad * 4;
#pragma unroll
        for (int j = 0; j < 4; ++j) {
            const size_t c = n0 + wn * 64 + j * 16 + lm;
            const int sel = (int)(c >> 10);       // 0=Q 1=K 2=V (uniform per j)
            const int col = (int)(c & 1023);
            const float bv = sel == 0 ? bQ[col] : (sel == 1 ? bK[col] : bV[col]);
#pragma unroll
            for (int t = 0; t < 4; ++t) {
                const size_t r = r0 + t;
                const u16 v = f2bf(acc[i][j][t] + bv);
                if (sel == 0)      Qb[r * (size_t)D_ + col] = v;
                else if (sel == 1) Kb[r * (size_t)D_ + col] = v;
                else {
                    const int h = col >> 6, dh = col & 63;
                    const int bb = (int)(r >> 11), s = (int)(r & 2047);
                    Vt[((size_t)((bb * 16 + h) * 64 + dh)) * S_ + s] = v;
                }
            }
        }
    }
}

// ---------------------------------------------------------------------------
// Flash attention, S^T formulation: grid (S/64, B*H); 4 waves x 16 queries.
// exp2-domain softmax, cvt_pk bf16 packing, defer-max rescale, dbuf LDS.
// ---------------------------------------------------------------------------
__global__ __launch_bounds__(256) void attn_kernel(
    const u16* __restrict__ Q, const u16* __restrict__ Kg,
    const u16* __restrict__ Vt, const float* __restrict__ mbias,
    u16* __restrict__ O)
{
    __shared__ alignas(16) u16 Kt[2][64 * 72];
    __shared__ alignas(16) u16 Vs[2][64 * 72];   // [dh][key]
    const int tid = threadIdx.x, w = tid >> 6, lane = tid & 63;
    const int lm = lane & 15, quad = lane >> 4;
    const int b = blockIdx.y >> 4, h = blockIdx.y & 15;
    const int q0 = blockIdx.x * 64;

    // Q B-frag: n = lane&15 -> query, k = quad*8+j -> dh
    const u16* qp = Q + ((size_t)(b * S_ + q0 + w * 16 + lm)) * D_ + h * 64;
    const short8 bq0 = *(const short8*)(qp + quad * 8);
    const short8 bq1 = *(const short8*)(qp + 32 + quad * 8);

    // staging: thread covers row tid>>2 (0..63), 16 u16 at col (tid&3)*16
    const int sRow = tid >> 2, sCol = (tid & 3) * 16;
    const u16* gK = Kg + ((size_t)(b * S_ + sRow)) * D_ + h * 64 + sCol;
    const u16* gV = Vt + ((size_t)((b * 16 + h) * 64 + sRow)) * S_ + sCol;

    float mrow = -1e30f, lrow = 0.f;
    floatx4 o[4];                                // o[dhs][reg], O^T layout
    const floatx4 z = {0.f, 0.f, 0.f, 0.f};
#pragma unroll
    for (int i = 0; i < 4; ++i) o[i] = z;

    const float* bp = mbias + b * S_;
    const float SCL = 0.18033688011112042f;      // 0.125 * log2(e)

    // prologue: tile 0 into registers
    short8 rk0 = *(const short8*)(gK);
    short8 rk1 = *(const short8*)(gK + 8);
    short8 rv0 = *(const short8*)(gV);
    short8 rv1 = *(const short8*)(gV + 8);

    for (int it = 0; it < NT_; ++it) {
        u16* kb = Kt[it & 1];
        u16* vb = Vs[it & 1];
        *(short8*)&kb[sRow * 72 + sCol]     = rk0;
        *(short8*)&kb[sRow * 72 + sCol + 8] = rk1;
        *(short8*)&vb[sRow * 72 + sCol]     = rv0;
        *(short8*)&vb[sRow * 72 + sCol + 8] = rv1;
        __syncthreads();
        if (it + 1 < NT_) {                      // issue next tile under compute
            gK += (size_t)64 * D_; gV += 64;
            rk0 = *(const short8*)(gK);
            rk1 = *(const short8*)(gK + 8);
            rv0 = *(const short8*)(gV);
            rv1 = *(const short8*)(gV + 8);
        }

        // S^T (64 keys x 16 queries): A = K-frag, B = Q-frag
        floatx4 st[4];
        __builtin_amdgcn_s_setprio(1);
#pragma unroll
        for (int ks = 0; ks < 4; ++ks) {
            floatx4 s = z;
            const short8 ak0 = *(const short8*)&kb[(ks * 16 + lm) * 72 + quad * 8];
            const short8 ak1 = *(const short8*)&kb[(ks * 16 + lm) * 72 + 32 + quad * 8];
            s = __builtin_amdgcn_mfma_f32_16x16x32_bf16(ak0, bq0, s, 0, 0, 0);
            s = __builtin_amdgcn_mfma_f32_16x16x32_bf16(ak1, bq1, s, 0, 0, 0);
            const float4 mb4 = *(const float4*)&bp[it * 64 + ks * 16 + quad * 4];
            st[ks][0] = fmaf(s[0], SCL, mb4.x);
            st[ks][1] = fmaf(s[1], SCL, mb4.y);
            st[ks][2] = fmaf(s[2], SCL, mb4.z);
            st[ks][3] = fmaf(s[3], SCL, mb4.w);
        }
        __builtin_amdgcn_s_setprio(0);

        // tile max, then cross-quad (xor 16, 32)
        float t0 = fmaxf(fmaxf(st[0][0], st[0][1]), st[0][2]);
        float t1 = fmaxf(fmaxf(st[0][3], st[1][0]), st[1][1]);
        float t2 = fmaxf(fmaxf(st[1][2], st[1][3]), st[2][0]);
        float t3 = fmaxf(fmaxf(st[2][1], st[2][2]), st[2][3]);
        float t4 = fmaxf(fmaxf(st[3][0], st[3][1]), st[3][2]);
        float tm = fmaxf(fmaxf(t0, t1), t2);
        tm = fmaxf(fmaxf(tm, t3), t4);
        tm = fmaxf(tm, st[3][3]);
        tm = fmaxf(tm, __shfl_xor(tm, 16));
        tm = fmaxf(tm, __shfl_xor(tm, 32));

        // defer-max: only rescale when the running max grew by > 8 (log2)
        if (!__all(tm <= mrow + 8.f)) {
            const float mn = fmaxf(mrow, tm);
            const float al = __builtin_amdgcn_exp2f(mrow - mn);
            mrow = mn;
            lrow *= al;
#pragma unroll
            for (int d = 0; d < 4; ++d) o[d] *= al;
        }

        float rs = 0.f;
#pragma unroll
        for (int ks = 0; ks < 4; ++ks)
#pragma unroll
            for (int r = 0; r < 4; ++r) {
                const float p = __builtin_amdgcn_exp2f(st[ks][r] - mrow);
                st[ks][r] = p; rs += p;
            }
        rs += __shfl_xor(rs, 16);
        rs += __shfl_xor(rs, 32);
        lrow += rs;

        // P^T B-frags for 16x16x16: k = quad*4+j (key), n = lm (query)
        short4v pb[4];
#pragma unroll
        for (int ks = 0; ks < 4; ++ks) {
            uint2 uu;
            uu.x = cvtpk_bf16(st[ks][0], st[ks][1]);
            uu.y = cvtpk_bf16(st[ks][2], st[ks][3]);
            pb[ks] = __builtin_bit_cast(short4v, uu);
        }
        // O^T += V^T · P^T ; V^T A-frag: m=dh (lm), k=key=quad*4+j (b64 read)
        __builtin_amdgcn_s_setprio(1);
#pragma unroll
        for (int d = 0; d < 4; ++d)
#pragma unroll
            for (int ks = 0; ks < 4; ++ks) {
                const short4v av = *(const short4v*)&vb[(d * 16 + lm) * 72 + ks * 16 + quad * 4];
                o[d] = __builtin_amdgcn_mfma_f32_16x16x16bf16_1k(av, pb[ks], o[d], 0, 0, 0);
            }
        __builtin_amdgcn_s_setprio(0);
    }
    // O^T C-layout: row=dh=quad*4+reg, col=query=lm -> 4 contiguous u16/store
    const float inv = __builtin_amdgcn_rcpf(lrow);
    u16* op = O + ((size_t)(b * S_ + q0 + w * 16 + lm)) * D_ + h * 64 + quad * 4;
#pragma unroll
    for (int d = 0; d < 4; ++d) {
        uint2 uu;
        uu.x = cvtpk_bf16(o[d][0] * inv, o[d][1] * inv);
        uu.y = cvtpk_bf16(o[d][2] * inv, o[d][3] * inv);
        *(uint2*)(op + d * 16) = uu;
    }
}

// ---------------------------------------------------------------------------
// out = LayerNorm(mainp + resid) * gamma + beta. (fallback, no partials)
// ---------------------------------------------------------------------------
template<bool MAIN_F32, bool RESID_F32, bool OUT_F32>
__global__ __launch_bounds__(256) void add_ln(
    const void* __restrict__ mainp, const void* __restrict__ resid,
    const float* __restrict__ gamma, const float* __restrict__ beta,
    void* __restrict__ out)
{
    const int row = blockIdx.x;
    const size_t base = (size_t)row * D_;
    const int t = threadIdx.x;
    const int w = t >> 6, lane = t & 63;
    float v[4];
#pragma unroll
    for (int i = 0; i < 4; ++i) {
        const int c = i * 256 + t;
        const float mv = MAIN_F32 ? ((const float*)mainp)[base + c]
                                  : bf2f(((const u16*)mainp)[base + c]);
        const float rv = RESID_F32 ? ((const float*)resid)[base + c]
                                   : bf2f(((const u16*)resid)[base + c]);
        v[i] = mv + rv;
    }
    float s = v[0] + v[1] + v[2] + v[3];
#pragma unroll
    for (int off = 32; off >= 1; off >>= 1) s += __shfl_xor(s, off);
    __shared__ float red[8];
    if (lane == 0) red[w] = s;
    __syncthreads();
    const float mean = (red[0] + red[1] + red[2] + red[3]) * (1.0f / D_);
    float q = 0.f;
#pragma unroll
    for (int i = 0; i < 4; ++i) { const float dd = v[i] - mean; q += dd * dd; }
#pragma unroll
    for (int off = 32; off >= 1; off >>= 1) q += __shfl_xor(q, off);
    if (lane == 0) red[4 + w] = q;
    __syncthreads();
    const float var = (red[4] + red[5] + red[6] + red[7]) * (1.0f / D_);
    const float rstd = rsqrtf(var + 1e-5f);
#pragma unroll
    for (int i = 0; i < 4; ++i) {
        const int c = i * 256 + t;
        const float o = (v[i] - mean) * rstd * gamma[c] + beta[c];
        if (OUT_F32) ((float*)out)[base + c] = o;
        else         ((u16*)out)[base + c] = f2bf(o);
    }
}

// ---------------------------------------------------------------------------
// out = LayerNorm(mainp + sum(Pext partials) + resid) * gamma + beta.
// Fused split-K reduction + add + LN. All partials f32.
// ---------------------------------------------------------------------------
template<int NEXT, bool RESID_F32, bool OUT_F32>
__global__ __launch_bounds__(256) void add_ln_red(
    const float* __restrict__ mainp, const float* __restrict__ Pext,
    const void* __restrict__ resid,
    const float* __restrict__ gamma, const float* __restrict__ beta,
    void* __restrict__ out)
{
    const int row = blockIdx.x;
    const size_t base = (size_t)row * D_;
    const int t = threadIdx.x;
    const int w = t >> 6, lane = t & 63;
    float v[4];
#pragma unroll
    for (int i = 0; i < 4; ++i) {
        const int c = i * 256 + t;
        float s = mainp[base + c];
#pragma unroll
        for (int p = 0; p < NEXT; ++p)
            s += Pext[(size_t)p * ((size_t)M_ * D_) + base + c];
        s += RESID_F32 ? ((const float*)resid)[base + c]
                       : bf2f(((const u16*)resid)[base + c]);
        v[i] = s;
    }
    float s = v[0] + v[1] + v[2] + v[3];
#pragma unroll
    for (int off = 32; off >= 1; off >>= 1) s += __shfl_xor(s, off);
    __shared__ float red[8];
    if (lane == 0) red[w] = s;
    __syncthreads();
    const float mean = (red[0] + red[1] + red[2] + red[3]) * (1.0f / D_);
    float q = 0.f;
#pragma unroll
    for (int i = 0; i < 4; ++i) { const float dd = v[i] - mean; q += dd * dd; }
#pragma unroll
    for (int off = 32; off >= 1; off >>= 1) q += __shfl_xor(q, off);
    if (lane == 0) red[4 + w] = q;
    __syncthreads();
    const float var = (red[4] + red[5] + red[6] + red[7]) * (1.0f / D_);
    const float rstd = rsqrtf(var + 1e-5f);
#pragma unroll
    for (int i = 0; i < 4; ++i) {
        const int c = i * 256 + t;
        const float o = (v[i] - mean) * rstd * gamma[c] + beta[c];
        if (OUT_F32) ((float*)out)[base + c] = o;
        else         ((u16*)out)[base + c] = f2bf(o);
    }
}

// ---------------------------------------------------------------------------
extern "C" void kernel_launch(void* const* d_in, const int* in_sizes, int n_in,
                              void* d_out, int out_size, void* d_ws, size_t ws_size,
                              hipStream_t stream)
{
    const float* x   = (const float*)d_in[0];
    const int* mask  = (const int*)d_in[1];
    const float* WQ = (const float*)d_in[2];  const float* bQ = (const float*)d_in[3];
    const float* WK = (const float*)d_in[4];  const float* bK = (const float*)d_in[5];
    const float* WV = (const float*)d_in[6];  const float* bV = (const float*)d_in[7];
    const float* WY = (const float*)d_in[8];  const float* bY = (const float*)d_in[9];
    const float* ln1w = (const float*)d_in[10]; const float* ln1b = (const float*)d_in[11];
    const float* ln2w = (const float*)d_in[12]; const float* ln2b = (const float*)d_in[13];
    const float* W1 = (const float*)d_in[14]; const float* b1 = (const float*)d_in[15];
    const float* W2 = (const float*)d_in[16]; const float* b2 = (const float*)d_in[17];

    // Workspace:
    //  [0,8)  xb -> W1t -> W2t
    //  [8,14) Wqkvt, [14,16) WYt -> hbf [8,16)
    //  [16,24) Qb, [24,32) Kb -> Ypf [16,32) -> G [16,48)
    //  [32,40) Vt, [40,48) Yat -> G
    //  [48, +16KB) mask bias
    //  [49, 49+NEXT*16) split-K partial buffers (gated on ws_size)
    char* ws = (char*)d_ws;
    u16* xb    = (u16*)(ws + 0  * MB_);
    u16* Wqkvt = (u16*)(ws + 8  * MB_);        // 6 MB: [WQ^T; WK^T; WV^T]
    u16* WYt   = (u16*)(ws + 14 * MB_);        // 2 MB
    u16* Qb    = (u16*)(ws + 16 * MB_);
    u16* Kb    = (u16*)(ws + 24 * MB_);
    u16* Vt    = (u16*)(ws + 32 * MB_);        // [b][h][dh][s]
    u16* Yat   = (u16*)(ws + 40 * MB_);
    float* Ypf = (float*)(ws + 16 * MB_);      // 16 MB f32, after Qb/Kb dead
    u16* hbf   = (u16*)(ws + 8  * MB_);        // after Wqkvt/WYt dead
    u16* W1t   = (u16*)(ws + 0  * MB_);        // after xb dead
    u16* G     = (u16*)(ws + 16 * MB_);        // after Ypf/Vt/Yat dead
    u16* W2t   = (u16*)(ws + 0  * MB_);        // after W1t dead
    float* mb  = (float*)(ws + 48 * MB_);      // 16 KB mask bias
    float* Pext = (float*)(ws + 49 * MB_);     // split-K partials (f32)

    const size_t PART = (size_t)M_ * D_ * sizeof(float);          // 16 MB
    const bool ws1 = ws_size >= 49 * MB_ + 1 * PART;              // >= 65 MB
    const bool ws3 = ws_size >= 49 * MB_ + 3 * PART;              // >= 97 MB

    const dim3 tb(32, 8);

    cvt_f32_bf16<<<(M_*D_)/1024, 256, 0, stream>>>(x, xb, M_*D_);
    mask_bias<<<(B_*S_)/256, 256, 0, stream>>>(mask, mb, B_*S_);
    transpose_cvt4<<<dim3(D_/32, D_/32, 4), tb, 0, stream>>>(WQ, WK, WV, WY, Wqkvt, WYt);

    gemm_qkv<<<dim3(3*D_/128, M_/128), 256, 0, stream>>>(xb, Wqkvt, bQ, bK, bV, Qb, Kb, Vt);

    attn_kernel<<<dim3(S_/64, B_*H_), 256, 0, stream>>>(Qb, Kb, Vt, mb, Yat);

    // ---- Y-proj (N=1024): split-K=2 ----
    if (ws1) {
        gemm_bt_skp<<<dim3(D_/128, M_/128, 2), 256, 0, stream>>>(
            Yat, WYt, bY, Ypf, Pext, M_, D_, D_);
        add_ln_red<1,true,false><<<M_, 256, 0, stream>>>(Ypf, Pext, x, ln1w, ln1b, hbf);
    } else {
        hipMemsetAsync(Ypf, 0, PART, stream);
        gemm_bt_sk2<<<dim3(D_/128, M_/128, 2), 256, 0, stream>>>(
            Yat, WYt, bY, Ypf, M_, D_, D_);
        add_ln<true,true,false><<<M_, 256, 0, stream>>>(Ypf, x, ln1w, ln1b, hbf);
    }

    transpose_cvt<<<dim3(FF_/32, D_/32), tb, 0, stream>>>(W1, W1t, D_, FF_);
    gemm_bt<true,false><<<dim3(FF_/128, M_/128), 256, 0, stream>>>(hbf, W1t, b1, G, M_, FF_, D_);

    transpose_cvt<<<dim3(D_/32, FF_/32), tb, 0, stream>>>(W2, W2t, FF_, D_);

    // ---- FF2 (N=1024, K=4096): split-K=4 (partials) if ws allows ----
    if (ws3) {
        gemm_bt_skp<<<dim3(D_/128, M_/128, 4), 256, 0, stream>>>(
            G, W2t, b2, (float*)d_out, Pext, M_, D_, FF_);
        add_ln_red<3,false,true><<<M_, 256, 0, stream>>>(
            (float*)d_out, Pext, hbf, ln2w, ln2b, d_out);
    } else if (ws1) {
        gemm_bt_skp<<<dim3(D_/128, M_/128, 2), 256, 0, stream>>>(
            G, W2t, b2, (float*)d_out, Pext, M_, D_, FF_);
        add_ln_red<1,false,true><<<M_, 256, 0, stream>>>(
            (float*)d_out, Pext, hbf, ln2w, ln2b, d_out);
    } else {
        hipMemsetAsync(d_out, 0, (size_t)M_ * D_ * 4, stream);
        gemm_bt_sk2<<<dim3(D_/128, M_/128, 2), 256, 0, stream>>>(
            G, W2t, b2, (float*)d_out, M_, D_, FF_);
        add_ln<true,false,true><<<M_, 256, 0, stream>>>(
            (float*)d_out, hbf, ln2w, ln2b, d_out);
    }
}

// Round 3
// 447.531 us; speedup vs baseline: 1.1182x; 1.0246x over previous
//
#include <hip/hip_runtime.h>
#include <cstdint>
#include <cstddef>

#define B_ 2
#define S_ 2048
#define D_ 1024
#define H_ 16
#define DH_ 64
#define FF_ 4096
#define M_ (B_*S_)
#define MB_ ((size_t)1 << 20)
#define NT_ (S_/64)

using u16 = unsigned short;
using short8 = __attribute__((ext_vector_type(8))) short;
using short4v = __attribute__((ext_vector_type(4))) short;
using floatx4 = __attribute__((ext_vector_type(4))) float;

__device__ __forceinline__ float bf2f(u16 u) {
    return __uint_as_float(((uint32_t)u) << 16);
}
__device__ __forceinline__ u16 f2bf(float f) {
    uint32_t u = __float_as_uint(f);
    u += 0x7fffu + ((u >> 16) & 1u);   // RNE
    return (u16)(u >> 16);
}
// pack two f32 -> bf16x2 in one VALU op (RNE)
__device__ __forceinline__ uint32_t cvtpk_bf16(float lo, float hi) {
    uint32_t r;
    asm("v_cvt_pk_bf16_f32 %0, %1, %2" : "=v"(r) : "v"(lo), "v"(hi));
    return r;
}
// async global->LDS, 16B per lane; LDS dest = wave-uniform base + lane*16
__device__ __forceinline__ void async_copy16(const u16* g, u16* l) {
    __builtin_amdgcn_global_load_lds(
        (const __attribute__((address_space(1))) uint32_t*)g,
        (__attribute__((address_space(3))) uint32_t*)l, 16, 0, 0);
}

// ---------------------------------------------------------------------------
// One K-step of the 2-phase double-buffered GEMM loop (T3 minimum recipe):
// issue next-tile global_load_lds FIRST, then ds_read+MFMA the current tile,
// then ONE __syncthreads() (compiler emits vmcnt(0) lgkmcnt(0) drain there).
// Loads overlap the MFMA cluster within the same wave.
// ---------------------------------------------------------------------------
__device__ __forceinline__ void gemm_step(
    const u16* Acur, const u16* Bcur, u16* Astg, u16* Bstg, bool pref,
    const u16*& gA, const u16*& gB, int K,
    int w, int wm, int wn, int lm, int quad, floatx4 (&acc)[4][4])
{
    if (pref) {
        async_copy16(gA, Astg + w * 512);
        async_copy16(gA + (size_t)64 * K, Astg + w * 512 + 2048);
        async_copy16(gB, Bstg + w * 512);
        async_copy16(gB + (size_t)64 * K, Bstg + w * 512 + 2048);
        gA += 32; gB += 32;
    }
    short8 af[4], bfr[4];
#pragma unroll
    for (int t4 = 0; t4 < 4; ++t4)
        af[t4] = *(const short8*)&Acur[(wm * 64 + t4 * 16 + lm) * 32 + quad * 8];
#pragma unroll
    for (int t4 = 0; t4 < 4; ++t4)
        bfr[t4] = *(const short8*)&Bcur[(wn * 64 + t4 * 16 + lm) * 32 + quad * 8];
#pragma unroll
    for (int i = 0; i < 4; ++i)
#pragma unroll
        for (int j = 0; j < 4; ++j)
            acc[i][j] = __builtin_amdgcn_mfma_f32_16x16x32_bf16(
                af[i], bfr[j], acc[i][j], 0, 0, 0);
    __syncthreads();
}

// ---------------------------------------------------------------------------
// f32 -> bf16 elementwise convert (x). n multiple of 1024.
// ---------------------------------------------------------------------------
__global__ __launch_bounds__(256) void cvt_f32_bf16(
    const float* __restrict__ in, u16* __restrict__ out, int n)
{
    const int i = (blockIdx.x * 256 + threadIdx.x) * 4;
    if (i < n) {
        const float4 v = *(const float4*)(in + i);
        out[i + 0] = f2bf(v.x);
        out[i + 1] = f2bf(v.y);
        out[i + 2] = f2bf(v.z);
        out[i + 3] = f2bf(v.w);
    }
}

// ---------------------------------------------------------------------------
// mask (int32) -> additive bias: 0 or -1e30
// ---------------------------------------------------------------------------
__global__ __launch_bounds__(256) void mask_bias(
    const int* __restrict__ mask, float* __restrict__ bias, int n)
{
    const int i = blockIdx.x * 256 + threadIdx.x;
    if (i < n) bias[i] = mask[i] ? 0.f : -1e30f;
}

// ---------------------------------------------------------------------------
// transpose+convert: in f32 (R x C) -> out bf16 (C x R)
// ---------------------------------------------------------------------------
__global__ void transpose_cvt(const float* __restrict__ in, u16* __restrict__ out,
                              int R, int C) {
    __shared__ float t[32][33];
    const int bx = blockIdx.x * 32, by = blockIdx.y * 32;
    const int tx = threadIdx.x, ty = threadIdx.y;
#pragma unroll
    for (int i = 0; i < 32; i += 8)
        t[ty + i][tx] = in[(size_t)(by + ty + i) * C + bx + tx];
    __syncthreads();
#pragma unroll
    for (int i = 0; i < 32; i += 8)
        out[(size_t)(bx + ty + i) * R + by + tx] = f2bf(t[tx][ty + i]);
}

// Fused transpose of the four D x D weights (WQ,WK,WV -> Wqkvt; WY -> WYt).
__global__ void transpose_cvt4(
    const float* __restrict__ WQ, const float* __restrict__ WK,
    const float* __restrict__ WV, const float* __restrict__ WY,
    u16* __restrict__ Wqkvt, u16* __restrict__ WYt)
{
    __shared__ float t[32][33];
    const int zz = blockIdx.z;
    const float* in = zz == 0 ? WQ : zz == 1 ? WK : zz == 2 ? WV : WY;
    u16* out = zz < 3 ? Wqkvt + (size_t)zz * D_ * D_ : WYt;
    const int bx = blockIdx.x * 32, by = blockIdx.y * 32;
    const int tx = threadIdx.x, ty = threadIdx.y;
#pragma unroll
    for (int i = 0; i < 32; i += 8)
        t[ty + i][tx] = in[(size_t)(by + ty + i) * D_ + bx + tx];
    __syncthreads();
#pragma unroll
    for (int i = 0; i < 32; i += 8)
        out[(size_t)(bx + ty + i) * D_ + by + tx] = f2bf(t[tx][ty + i]);
}

// ---------------------------------------------------------------------------
// Generic GEMM: C(MxN) = A(MxK) @ W + bias; W as Wt (NxK bf16), bias f32.
// 128x128 tile, BK=32, 4 waves, mfma 16x16x32 bf16. 2-phase dbuf pipeline.
// ---------------------------------------------------------------------------
template<bool GELU, bool OUT_F32>
__global__ __launch_bounds__(256) void gemm_bt(
    const u16* __restrict__ A, const u16* __restrict__ Bt,
    const float* __restrict__ bias, void* __restrict__ Cout,
    int M, int N, int K)
{
    __shared__ alignas(16) u16 As[2][128 * 32];
    __shared__ alignas(16) u16 Bs[2][128 * 32];
    const int tid = threadIdx.x;
    const int w = tid >> 6, lane = tid & 63;
    const int lm = lane & 15, quad = lane >> 4;
    const int wm = w >> 1, wn = w & 1;

    // XCD-chunked swizzle (bijective when nwg % 8 == 0)
    const int nwg = gridDim.x * gridDim.y;
    int bid = blockIdx.y * gridDim.x + blockIdx.x;
    if ((nwg & 7) == 0) {
        const int cpx = nwg >> 3;
        bid = (bid & 7) * cpx + (bid >> 3);
    }
    const int bx = bid % gridDim.x, by = bid / gridDim.x;
    const size_t m0 = (size_t)by * 128, n0 = (size_t)bx * 128;

    const int rowS = w * 16 + (lane >> 2);
    const int colS = (lane & 3) * 8;
    const u16* gA = A + (m0 + rowS) * K + colS;
    const u16* gB = Bt + (n0 + rowS) * K + colS;

    floatx4 acc[4][4];
    const floatx4 z = {0.f, 0.f, 0.f, 0.f};
#pragma unroll
    for (int i = 0; i < 4; ++i)
#pragma unroll
        for (int j = 0; j < 4; ++j) acc[i][j] = z;

    // prologue: stage tile 0 into buffer 0
    async_copy16(gA, &As[0][w * 512]);
    async_copy16(gA + (size_t)64 * K, &As[0][w * 512 + 2048]);
    async_copy16(gB, &Bs[0][w * 512]);
    async_copy16(gB + (size_t)64 * K, &Bs[0][w * 512 + 2048]);
    gA += 32; gB += 32;
    __syncthreads();

    const int nk = K >> 5;                        // even for all our shapes
    for (int t = 0; t < nk; t += 2) {
        gemm_step(As[0], Bs[0], As[1], Bs[1], true,
                  gA, gB, K, w, wm, wn, lm, quad, acc);
        gemm_step(As[1], Bs[1], As[0], Bs[0], t + 2 < nk,
                  gA, gB, K, w, wm, wn, lm, quad, acc);
    }

#pragma unroll
    for (int i = 0; i < 4; ++i) {
        const size_t r0 = m0 + wm * 64 + i * 16 + quad * 4;
#pragma unroll
        for (int j = 0; j < 4; ++j) {
            const size_t c = n0 + wn * 64 + j * 16 + lm;
            const float bv = bias[c];
#pragma unroll
            for (int t = 0; t < 4; ++t) {
                float v = acc[i][j][t] + bv;
                if (GELU) v = 0.5f * v * (1.f + erff(v * 0.70710678118f));
                if (OUT_F32) ((float*)Cout)[(r0 + t) * (size_t)N + c] = v;
                else         ((u16*)Cout)[(r0 + t) * (size_t)N + c] = f2bf(v);
            }
        }
    }
}

// ---------------------------------------------------------------------------
// Split-K GEMM with PARTIAL STORES (no atomics). gridDim.z = nsplit.
// kh==0 writes out0 (+bias); kh>0 writes Pext + (kh-1)*M*N. 2-phase dbuf.
// ---------------------------------------------------------------------------
__global__ __launch_bounds__(256) void gemm_bt_skp(
    const u16* __restrict__ A, const u16* __restrict__ Bt,
    const float* __restrict__ bias, float* __restrict__ out0,
    float* __restrict__ Pext, int M, int N, int K)
{
    __shared__ alignas(16) u16 As[2][128 * 32];
    __shared__ alignas(16) u16 Bs[2][128 * 32];
    const int tid = threadIdx.x;
    const int w = tid >> 6, lane = tid & 63;
    const int lm = lane & 15, quad = lane >> 4;
    const int wm = w >> 1, wn = w & 1;
    const int kh = blockIdx.z;
    const int Ks = K / gridDim.z;

    const int nwg = gridDim.x * gridDim.y;
    int bid = blockIdx.y * gridDim.x + blockIdx.x;
    if ((nwg & 7) == 0) {
        const int cpx = nwg >> 3;
        bid = (bid & 7) * cpx + (bid >> 3);
    }
    const int bx = bid % gridDim.x, by = bid / gridDim.x;
    const size_t m0 = (size_t)by * 128, n0 = (size_t)bx * 128;

    const int rowS = w * 16 + (lane >> 2);
    const int colS = (lane & 3) * 8;
    const u16* gA = A + (m0 + rowS) * K + (size_t)kh * Ks + colS;
    const u16* gB = Bt + (n0 + rowS) * K + (size_t)kh * Ks + colS;

    floatx4 acc[4][4];
    const floatx4 z = {0.f, 0.f, 0.f, 0.f};
#pragma unroll
    for (int i = 0; i < 4; ++i)
#pragma unroll
        for (int j = 0; j < 4; ++j) acc[i][j] = z;

    async_copy16(gA, &As[0][w * 512]);
    async_copy16(gA + (size_t)64 * K, &As[0][w * 512 + 2048]);
    async_copy16(gB, &Bs[0][w * 512]);
    async_copy16(gB + (size_t)64 * K, &Bs[0][w * 512 + 2048]);
    gA += 32; gB += 32;
    __syncthreads();

    const int nk = Ks >> 5;
    for (int t = 0; t < nk; t += 2) {
        gemm_step(As[0], Bs[0], As[1], Bs[1], true,
                  gA, gB, K, w, wm, wn, lm, quad, acc);
        gemm_step(As[1], Bs[1], As[0], Bs[0], t + 2 < nk,
                  gA, gB, K, w, wm, wn, lm, quad, acc);
    }

    float* Cout = (kh == 0) ? out0 : Pext + (size_t)(kh - 1) * ((size_t)M * N);
#pragma unroll
    for (int i = 0; i < 4; ++i) {
        const size_t r0 = m0 + wm * 64 + i * 16 + quad * 4;
#pragma unroll
        for (int j = 0; j < 4; ++j) {
            const size_t c = n0 + wn * 64 + j * 16 + lm;
            const float bv = (kh == 0) ? bias[c] : 0.f;
#pragma unroll
            for (int t = 0; t < 4; ++t)
                Cout[(r0 + t) * (size_t)N + c] = acc[i][j][t] + bv;
        }
    }
}

// ---------------------------------------------------------------------------
// Fallback: split-K=2 GEMM, atomic f32 accumulate (used when ws too small).
// ---------------------------------------------------------------------------
__global__ __launch_bounds__(256) void gemm_bt_sk2(
    const u16* __restrict__ A, const u16* __restrict__ Bt,
    const float* __restrict__ bias, float* __restrict__ Cout,
    int M, int N, int K)
{
    __shared__ alignas(16) u16 As[2][128 * 32];
    __shared__ alignas(16) u16 Bs[2][128 * 32];
    const int tid = threadIdx.x;
    const int w = tid >> 6, lane = tid & 63;
    const int lm = lane & 15, quad = lane >> 4;
    const int wm = w >> 1, wn = w & 1;
    const int kh = blockIdx.z;
    const int Ks = K >> 1;
    const size_t m0 = (size_t)blockIdx.y * 128, n0 = (size_t)blockIdx.x * 128;

    const int rowS = w * 16 + (lane >> 2);
    const int colS = (lane & 3) * 8;
    const u16* gA = A + (m0 + rowS) * K + (size_t)kh * Ks + colS;
    const u16* gB = Bt + (n0 + rowS) * K + (size_t)kh * Ks + colS;

    floatx4 acc[4][4];
    const floatx4 z = {0.f, 0.f, 0.f, 0.f};
#pragma unroll
    for (int i = 0; i < 4; ++i)
#pragma unroll
        for (int j = 0; j < 4; ++j) acc[i][j] = z;

    async_copy16(gA, &As[0][w * 512]);
    async_copy16(gA + (size_t)64 * K, &As[0][w * 512 + 2048]);
    async_copy16(gB, &Bs[0][w * 512]);
    async_copy16(gB + (size_t)64 * K, &Bs[0][w * 512 + 2048]);
    gA += 32; gB += 32;
    __syncthreads();

    const int nk = Ks >> 5;
    for (int t = 0; t < nk; t += 2) {
        gemm_step(As[0], Bs[0], As[1], Bs[1], true,
                  gA, gB, K, w, wm, wn, lm, quad, acc);
        gemm_step(As[1], Bs[1], As[0], Bs[0], t + 2 < nk,
                  gA, gB, K, w, wm, wn, lm, quad, acc);
    }

#pragma unroll
    for (int i = 0; i < 4; ++i) {
        const size_t r0 = m0 + wm * 64 + i * 16 + quad * 4;
#pragma unroll
        for (int j = 0; j < 4; ++j) {
            const size_t c = n0 + wn * 64 + j * 16 + lm;
            const float bv = (kh == 0) ? bias[c] : 0.f;
#pragma unroll
            for (int t = 0; t < 4; ++t)
                atomicAdd(&Cout[(r0 + t) * (size_t)N + c], acc[i][j][t] + bv);
        }
    }
}

// ---------------------------------------------------------------------------
// Fused QKV GEMM: A(M x 1024) @ Wqkv (1024 x 3072), Wqkvt rows: [WQ^T;WK^T;WV^T].
// Q,K written [m][1024]; V written transposed per head: Vt[((b*16+h)*64+dh)*S + s].
// ---------------------------------------------------------------------------
__global__ __launch_bounds__(256) void gemm_qkv(
    const u16* __restrict__ A, const u16* __restrict__ Bt,
    const float* __restrict__ bQ, const float* __restrict__ bK,
    const float* __restrict__ bV,
    u16* __restrict__ Qb, u16* __restrict__ Kb, u16* __restrict__ Vt)
{
    const int K = D_, N = 3 * D_;
    __shared__ alignas(16) u16 As[2][128 * 32];
    __shared__ alignas(16) u16 Bs[2][128 * 32];
    const int tid = threadIdx.x;
    const int w = tid >> 6, lane = tid & 63;
    const int lm = lane & 15, quad = lane >> 4;
    const int wm = w >> 1, wn = w & 1;

    const int nwg = gridDim.x * gridDim.y;
    int bid = blockIdx.y * gridDim.x + blockIdx.x;
    if ((nwg & 7) == 0) {
        const int cpx = nwg >> 3;
        bid = (bid & 7) * cpx + (bid >> 3);
    }
    const int bx = bid % gridDim.x, by = bid / gridDim.x;
    const size_t m0 = (size_t)by * 128, n0 = (size_t)bx * 128;

    const int rowS = w * 16 + (lane >> 2);
    const int colS = (lane & 3) * 8;
    const u16* gA = A + (m0 + rowS) * K + colS;
    const u16* gB = Bt + (n0 + rowS) * K + colS;

    floatx4 acc[4][4];
    const floatx4 z = {0.f, 0.f, 0.f, 0.f};
#pragma unroll
    for (int i = 0; i < 4; ++i)
#pragma unroll
        for (int j = 0; j < 4; ++j) acc[i][j] = z;

    async_copy16(gA, &As[0][w * 512]);
    async_copy16(gA + (size_t)64 * K, &As[0][w * 512 + 2048]);
    async_copy16(gB, &Bs[0][w * 512]);
    async_copy16(gB + (size_t)64 * K, &Bs[0][w * 512 + 2048]);
    gA += 32; gB += 32;
    __syncthreads();

    const int nk = K >> 5;
    for (int t = 0; t < nk; t += 2) {
        gemm_step(As[0], Bs[0], As[1], Bs[1], true,
                  gA, gB, K, w, wm, wn, lm, quad, acc);
        gemm_step(As[1], Bs[1], As[0], Bs[0], t + 2 < nk,
                  gA, gB, K, w, wm, wn, lm, quad, acc);
    }

#pragma unroll
    for (int i = 0; i < 4; ++i) {
        const size_t r0 = m0 + wm * 64 + i * 16 + quad * 4;
#pragma unroll
        for (int j = 0; j < 4; ++j) {
            const size_t c = n0 + wn * 64 + j * 16 + lm;
            const int sel = (int)(c >> 10);       // 0=Q 1=K 2=V (uniform per j)
            const int col = (int)(c & 1023);
            const float bv = sel == 0 ? bQ[col] : (sel == 1 ? bK[col] : bV[col]);
#pragma unroll
            for (int t = 0; t < 4; ++t) {
                const size_t r = r0 + t;
                const u16 v = f2bf(acc[i][j][t] + bv);
                if (sel == 0)      Qb[r * (size_t)D_ + col] = v;
                else if (sel == 1) Kb[r * (size_t)D_ + col] = v;
                else {
                    const int h = col >> 6, dh = col & 63;
                    const int bb = (int)(r >> 11), s = (int)(r & 2047);
                    Vt[((size_t)((bb * 16 + h) * 64 + dh)) * S_ + s] = v;
                }
            }
        }
    }
}

// ---------------------------------------------------------------------------
// Flash attention, S^T formulation: grid (S/64, B*H); 4 waves x 16 queries.
// exp2-domain softmax, cvt_pk bf16 packing, defer-max rescale, dbuf LDS.
// ---------------------------------------------------------------------------
__global__ __launch_bounds__(256) void attn_kernel(
    const u16* __restrict__ Q, const u16* __restrict__ Kg,
    const u16* __restrict__ Vt, const float* __restrict__ mbias,
    u16* __restrict__ O)
{
    __shared__ alignas(16) u16 Kt[2][64 * 72];
    __shared__ alignas(16) u16 Vs[2][64 * 72];   // [dh][key]
    const int tid = threadIdx.x, w = tid >> 6, lane = tid & 63;
    const int lm = lane & 15, quad = lane >> 4;
    const int b = blockIdx.y >> 4, h = blockIdx.y & 15;
    const int q0 = blockIdx.x * 64;

    // Q B-frag: n = lane&15 -> query, k = quad*8+j -> dh
    const u16* qp = Q + ((size_t)(b * S_ + q0 + w * 16 + lm)) * D_ + h * 64;
    const short8 bq0 = *(const short8*)(qp + quad * 8);
    const short8 bq1 = *(const short8*)(qp + 32 + quad * 8);

    // staging: thread covers row tid>>2 (0..63), 16 u16 at col (tid&3)*16
    const int sRow = tid >> 2, sCol = (tid & 3) * 16;
    const u16* gK = Kg + ((size_t)(b * S_ + sRow)) * D_ + h * 64 + sCol;
    const u16* gV = Vt + ((size_t)((b * 16 + h) * 64 + sRow)) * S_ + sCol;

    float mrow = -1e30f, lrow = 0.f;
    floatx4 o[4];                                // o[dhs][reg], O^T layout
    const floatx4 z = {0.f, 0.f, 0.f, 0.f};
#pragma unroll
    for (int i = 0; i < 4; ++i) o[i] = z;

    const float* bp = mbias + b * S_;
    const float SCL = 0.18033688011112042f;      // 0.125 * log2(e)

    // prologue: tile 0 into registers
    short8 rk0 = *(const short8*)(gK);
    short8 rk1 = *(const short8*)(gK + 8);
    short8 rv0 = *(const short8*)(gV);
    short8 rv1 = *(const short8*)(gV + 8);

    for (int it = 0; it < NT_; ++it) {
        u16* kb = Kt[it & 1];
        u16* vb = Vs[it & 1];
        *(short8*)&kb[sRow * 72 + sCol]     = rk0;
        *(short8*)&kb[sRow * 72 + sCol + 8] = rk1;
        *(short8*)&vb[sRow * 72 + sCol]     = rv0;
        *(short8*)&vb[sRow * 72 + sCol + 8] = rv1;
        __syncthreads();
        if (it + 1 < NT_) {                      // issue next tile under compute
            gK += (size_t)64 * D_; gV += 64;
            rk0 = *(const short8*)(gK);
            rk1 = *(const short8*)(gK + 8);
            rv0 = *(const short8*)(gV);
            rv1 = *(const short8*)(gV + 8);
        }

        // S^T (64 keys x 16 queries): A = K-frag, B = Q-frag
        floatx4 st[4];
        __builtin_amdgcn_s_setprio(1);
#pragma unroll
        for (int ks = 0; ks < 4; ++ks) {
            floatx4 s = z;
            const short8 ak0 = *(const short8*)&kb[(ks * 16 + lm) * 72 + quad * 8];
            const short8 ak1 = *(const short8*)&kb[(ks * 16 + lm) * 72 + 32 + quad * 8];
            s = __builtin_amdgcn_mfma_f32_16x16x32_bf16(ak0, bq0, s, 0, 0, 0);
            s = __builtin_amdgcn_mfma_f32_16x16x32_bf16(ak1, bq1, s, 0, 0, 0);
            const float4 mb4 = *(const float4*)&bp[it * 64 + ks * 16 + quad * 4];
            st[ks][0] = fmaf(s[0], SCL, mb4.x);
            st[ks][1] = fmaf(s[1], SCL, mb4.y);
            st[ks][2] = fmaf(s[2], SCL, mb4.z);
            st[ks][3] = fmaf(s[3], SCL, mb4.w);
        }
        __builtin_amdgcn_s_setprio(0);

        // tile max, then cross-quad (xor 16, 32)
        float t0 = fmaxf(fmaxf(st[0][0], st[0][1]), st[0][2]);
        float t1 = fmaxf(fmaxf(st[0][3], st[1][0]), st[1][1]);
        float t2 = fmaxf(fmaxf(st[1][2], st[1][3]), st[2][0]);
        float t3 = fmaxf(fmaxf(st[2][1], st[2][2]), st[2][3]);
        float t4 = fmaxf(fmaxf(st[3][0], st[3][1]), st[3][2]);
        float tm = fmaxf(fmaxf(t0, t1), t2);
        tm = fmaxf(fmaxf(tm, t3), t4);
        tm = fmaxf(tm, st[3][3]);
        tm = fmaxf(tm, __shfl_xor(tm, 16));
        tm = fmaxf(tm, __shfl_xor(tm, 32));

        // defer-max: only rescale when the running max grew by > 8 (log2)
        if (!__all(tm <= mrow + 8.f)) {
            const float mn = fmaxf(mrow, tm);
            const float al = __builtin_amdgcn_exp2f(mrow - mn);
            mrow = mn;
            lrow *= al;
#pragma unroll
            for (int d = 0; d < 4; ++d) o[d] *= al;
        }

        float rs = 0.f;
#pragma unroll
        for (int ks = 0; ks < 4; ++ks)
#pragma unroll
            for (int r = 0; r < 4; ++r) {
                const float p = __builtin_amdgcn_exp2f(st[ks][r] - mrow);
                st[ks][r] = p; rs += p;
            }
        rs += __shfl_xor(rs, 16);
        rs += __shfl_xor(rs, 32);
        lrow += rs;

        // P^T B-frags for 16x16x16: k = quad*4+j (key), n = lm (query)
        short4v pb[4];
#pragma unroll
        for (int ks = 0; ks < 4; ++ks) {
            uint2 uu;
            uu.x = cvtpk_bf16(st[ks][0], st[ks][1]);
            uu.y = cvtpk_bf16(st[ks][2], st[ks][3]);
            pb[ks] = __builtin_bit_cast(short4v, uu);
        }
        // O^T += V^T · P^T ; V^T A-frag: m=dh (lm), k=key=quad*4+j (b64 read)
        __builtin_amdgcn_s_setprio(1);
#pragma unroll
        for (int d = 0; d < 4; ++d)
#pragma unroll
            for (int ks = 0; ks < 4; ++ks) {
                const short4v av = *(const short4v*)&vb[(d * 16 + lm) * 72 + ks * 16 + quad * 4];
                o[d] = __builtin_amdgcn_mfma_f32_16x16x16bf16_1k(av, pb[ks], o[d], 0, 0, 0);
            }
        __builtin_amdgcn_s_setprio(0);
    }
    // O^T C-layout: row=dh=quad*4+reg, col=query=lm -> 4 contiguous u16/store
    const float inv = __builtin_amdgcn_rcpf(lrow);
    u16* op = O + ((size_t)(b * S_ + q0 + w * 16 + lm)) * D_ + h * 64 + quad * 4;
#pragma unroll
    for (int d = 0; d < 4; ++d) {
        uint2 uu;
        uu.x = cvtpk_bf16(o[d][0] * inv, o[d][1] * inv);
        uu.y = cvtpk_bf16(o[d][2] * inv, o[d][3] * inv);
        *(uint2*)(op + d * 16) = uu;
    }
}

// ---------------------------------------------------------------------------
// out = LayerNorm(mainp + resid) * gamma + beta. (fallback, no partials)
// ---------------------------------------------------------------------------
template<bool MAIN_F32, bool RESID_F32, bool OUT_F32>
__global__ __launch_bounds__(256) void add_ln(
    const void* __restrict__ mainp, const void* __restrict__ resid,
    const float* __restrict__ gamma, const float* __restrict__ beta,
    void* __restrict__ out)
{
    const int row = blockIdx.x;
    const size_t base = (size_t)row * D_;
    const int t = threadIdx.x;
    const int w = t >> 6, lane = t & 63;
    float v[4];
#pragma unroll
    for (int i = 0; i < 4; ++i) {
        const int c = i * 256 + t;
        const float mv = MAIN_F32 ? ((const float*)mainp)[base + c]
                                  : bf2f(((const u16*)mainp)[base + c]);
        const float rv = RESID_F32 ? ((const float*)resid)[base + c]
                                   : bf2f(((const u16*)resid)[base + c]);
        v[i] = mv + rv;
    }
    float s = v[0] + v[1] + v[2] + v[3];
#pragma unroll
    for (int off = 32; off >= 1; off >>= 1) s += __shfl_xor(s, off);
    __shared__ float red[8];
    if (lane == 0) red[w] = s;
    __syncthreads();
    const float mean = (red[0] + red[1] + red[2] + red[3]) * (1.0f / D_);
    float q = 0.f;
#pragma unroll
    for (int i = 0; i < 4; ++i) { const float dd = v[i] - mean; q += dd * dd; }
#pragma unroll
    for (int off = 32; off >= 1; off >>= 1) q += __shfl_xor(q, off);
    if (lane == 0) red[4 + w] = q;
    __syncthreads();
    const float var = (red[4] + red[5] + red[6] + red[7]) * (1.0f / D_);
    const float rstd = rsqrtf(var + 1e-5f);
#pragma unroll
    for (int i = 0; i < 4; ++i) {
        const int c = i * 256 + t;
        const float o = (v[i] - mean) * rstd * gamma[c] + beta[c];
        if (OUT_F32) ((float*)out)[base + c] = o;
        else         ((u16*)out)[base + c] = f2bf(o);
    }
}

// ---------------------------------------------------------------------------
// out = LayerNorm(mainp + sum(Pext partials) + resid) * gamma + beta.
// Fused split-K reduction + add + LN. All partials f32.
// ---------------------------------------------------------------------------
template<int NEXT, bool RESID_F32, bool OUT_F32>
__global__ __launch_bounds__(256) void add_ln_red(
    const float* __restrict__ mainp, const float* __restrict__ Pext,
    const void* __restrict__ resid,
    const float* __restrict__ gamma, const float* __restrict__ beta,
    void* __restrict__ out)
{
    const int row = blockIdx.x;
    const size_t base = (size_t)row * D_;
    const int t = threadIdx.x;
    const int w = t >> 6, lane = t & 63;
    float v[4];
#pragma unroll
    for (int i = 0; i < 4; ++i) {
        const int c = i * 256 + t;
        float s = mainp[base + c];
#pragma unroll
        for (int p = 0; p < NEXT; ++p)
            s += Pext[(size_t)p * ((size_t)M_ * D_) + base + c];
        s += RESID_F32 ? ((const float*)resid)[base + c]
                       : bf2f(((const u16*)resid)[base + c]);
        v[i] = s;
    }
    float s = v[0] + v[1] + v[2] + v[3];
#pragma unroll
    for (int off = 32; off >= 1; off >>= 1) s += __shfl_xor(s, off);
    __shared__ float red[8];
    if (lane == 0) red[w] = s;
    __syncthreads();
    const float mean = (red[0] + red[1] + red[2] + red[3]) * (1.0f / D_);
    float q = 0.f;
#pragma unroll
    for (int i = 0; i < 4; ++i) { const float dd = v[i] - mean; q += dd * dd; }
#pragma unroll
    for (int off = 32; off >= 1; off >>= 1) q += __shfl_xor(q, off);
    if (lane == 0) red[4 + w] = q;
    __syncthreads();
    const float var = (red[4] + red[5] + red[6] + red[7]) * (1.0f / D_);
    const float rstd = rsqrtf(var + 1e-5f);
#pragma unroll
    for (int i = 0; i < 4; ++i) {
        const int c = i * 256 + t;
        const float o = (v[i] - mean) * rstd * gamma[c] + beta[c];
        if (OUT_F32) ((float*)out)[base + c] = o;
        else         ((u16*)out)[base + c] = f2bf(o);
    }
}

// ---------------------------------------------------------------------------
extern "C" void kernel_launch(void* const* d_in, const int* in_sizes, int n_in,
                              void* d_out, int out_size, void* d_ws, size_t ws_size,
                              hipStream_t stream)
{
    const float* x   = (const float*)d_in[0];
    const int* mask  = (const int*)d_in[1];
    const float* WQ = (const float*)d_in[2];  const float* bQ = (const float*)d_in[3];
    const float* WK = (const float*)d_in[4];  const float* bK = (const float*)d_in[5];
    const float* WV = (const float*)d_in[6];  const float* bV = (const float*)d_in[7];
    const float* WY = (const float*)d_in[8];  const float* bY = (const float*)d_in[9];
    const float* ln1w = (const float*)d_in[10]; const float* ln1b = (const float*)d_in[11];
    const float* ln2w = (const float*)d_in[12]; const float* ln2b = (const float*)d_in[13];
    const float* W1 = (const float*)d_in[14]; const float* b1 = (const float*)d_in[15];
    const float* W2 = (const float*)d_in[16]; const float* b2 = (const float*)d_in[17];

    // Workspace:
    //  [0,8)  xb -> W1t -> W2t
    //  [8,14) Wqkvt, [14,16) WYt -> hbf [8,16)
    //  [16,24) Qb, [24,32) Kb -> Ypf [16,32) -> G [16,48)
    //  [32,40) Vt, [40,48) Yat -> G
    //  [48, +16KB) mask bias
    //  [49, 49+NEXT*16) split-K partial buffers (gated on ws_size)
    char* ws = (char*)d_ws;
    u16* xb    = (u16*)(ws + 0  * MB_);
    u16* Wqkvt = (u16*)(ws + 8  * MB_);        // 6 MB: [WQ^T; WK^T; WV^T]
    u16* WYt   = (u16*)(ws + 14 * MB_);        // 2 MB
    u16* Qb    = (u16*)(ws + 16 * MB_);
    u16* Kb    = (u16*)(ws + 24 * MB_);
    u16* Vt    = (u16*)(ws + 32 * MB_);        // [b][h][dh][s]
    u16* Yat   = (u16*)(ws + 40 * MB_);
    float* Ypf = (float*)(ws + 16 * MB_);      // 16 MB f32, after Qb/Kb dead
    u16* hbf   = (u16*)(ws + 8  * MB_);        // after Wqkvt/WYt dead
    u16* W1t   = (u16*)(ws + 0  * MB_);        // after xb dead
    u16* G     = (u16*)(ws + 16 * MB_);        // after Ypf/Vt/Yat dead
    u16* W2t   = (u16*)(ws + 0  * MB_);        // after W1t dead
    float* mb  = (float*)(ws + 48 * MB_);      // 16 KB mask bias
    float* Pext = (float*)(ws + 49 * MB_);     // split-K partials (f32)

    const size_t PART = (size_t)M_ * D_ * sizeof(float);          // 16 MB
    const bool ws1 = ws_size >= 49 * MB_ + 1 * PART;              // >= 65 MB
    const bool ws3 = ws_size >= 49 * MB_ + 3 * PART;              // >= 97 MB

    const dim3 tb(32, 8);

    cvt_f32_bf16<<<(M_*D_)/1024, 256, 0, stream>>>(x, xb, M_*D_);
    mask_bias<<<(B_*S_)/256, 256, 0, stream>>>(mask, mb, B_*S_);
    transpose_cvt4<<<dim3(D_/32, D_/32, 4), tb, 0, stream>>>(WQ, WK, WV, WY, Wqkvt, WYt);

    gemm_qkv<<<dim3(3*D_/128, M_/128), 256, 0, stream>>>(xb, Wqkvt, bQ, bK, bV, Qb, Kb, Vt);

    attn_kernel<<<dim3(S_/64, B_*H_), 256, 0, stream>>>(Qb, Kb, Vt, mb, Yat);

    // ---- Y-proj (N=1024): split-K=2 ----
    if (ws1) {
        gemm_bt_skp<<<dim3(D_/128, M_/128, 2), 256, 0, stream>>>(
            Yat, WYt, bY, Ypf, Pext, M_, D_, D_);
        add_ln_red<1,true,false><<<M_, 256, 0, stream>>>(Ypf, Pext, x, ln1w, ln1b, hbf);
    } else {
        hipMemsetAsync(Ypf, 0, PART, stream);
        gemm_bt_sk2<<<dim3(D_/128, M_/128, 2), 256, 0, stream>>>(
            Yat, WYt, bY, Ypf, M_, D_, D_);
        add_ln<true,true,false><<<M_, 256, 0, stream>>>(Ypf, x, ln1w, ln1b, hbf);
    }

    transpose_cvt<<<dim3(FF_/32, D_/32), tb, 0, stream>>>(W1, W1t, D_, FF_);
    gemm_bt<true,false><<<dim3(FF_/128, M_/128), 256, 0, stream>>>(hbf, W1t, b1, G, M_, FF_, D_);

    transpose_cvt<<<dim3(D_/32, FF_/32), tb, 0, stream>>>(W2, W2t, FF_, D_);

    // ---- FF2 (N=1024, K=4096): split-K=4 (partials) if ws allows ----
    if (ws3) {
        gemm_bt_skp<<<dim3(D_/128, M_/128, 4), 256, 0, stream>>>(
            G, W2t, b2, (float*)d_out, Pext, M_, D_, FF_);
        add_ln_red<3,false,true><<<M_, 256, 0, stream>>>(
            (float*)d_out, Pext, hbf, ln2w, ln2b, d_out);
    } else if (ws1) {
        gemm_bt_skp<<<dim3(D_/128, M_/128, 2), 256, 0, stream>>>(
            G, W2t, b2, (float*)d_out, Pext, M_, D_, FF_);
        add_ln_red<1,false,true><<<M_, 256, 0, stream>>>(
            (float*)d_out, Pext, hbf, ln2w, ln2b, d_out);
    } else {
        hipMemsetAsync(d_out, 0, (size_t)M_ * D_ * 4, stream);
        gemm_bt_sk2<<<dim3(D_/128, M_/128, 2), 256, 0, stream>>>(
            G, W2t, b2, (float*)d_out, M_, D_, FF_);
        add_ln<true,false,true><<<M_, 256, 0, stream>>>(
            (float*)d_out, hbf, ln2w, ln2b, d_out);
    }
}

// Round 4
// 405.401 us; speedup vs baseline: 1.2344x; 1.1039x over previous
//
#include <hip/hip_runtime.h>
#include <cstdint>
#include <cstddef>

#define B_ 2
#define S_ 2048
#define D_ 1024
#define H_ 16
#define DH_ 64
#define FF_ 4096
#define M_ (B_*S_)
#define MB_ ((size_t)1 << 20)
#define NT_ (S_/64)

using u16 = unsigned short;
using short8 = __attribute__((ext_vector_type(8))) short;
using short4v = __attribute__((ext_vector_type(4))) short;
using floatx4 = __attribute__((ext_vector_type(4))) float;

__device__ __forceinline__ float bf2f(u16 u) {
    return __uint_as_float(((uint32_t)u) << 16);
}
__device__ __forceinline__ u16 f2bf(float f) {
    uint32_t u = __float_as_uint(f);
    u += 0x7fffu + ((u >> 16) & 1u);   // RNE
    return (u16)(u >> 16);
}
// pack two f32 -> bf16x2 in one VALU op (RNE)
__device__ __forceinline__ uint32_t cvtpk_bf16(float lo, float hi) {
    uint32_t r;
    asm("v_cvt_pk_bf16_f32 %0, %1, %2" : "=v"(r) : "v"(lo), "v"(hi));
    return r;
}
// async global->LDS, 16B per lane; LDS dest = wave-uniform base + lane*16
__device__ __forceinline__ void async_copy16(const u16* g, u16* l) {
    __builtin_amdgcn_global_load_lds(
        (const __attribute__((address_space(1))) uint32_t*)g,
        (__attribute__((address_space(3))) uint32_t*)l, 16, 0, 0);
}

// GELU via Abramowitz-Stegun 7.1.26 erf (|eps| <= 1.5e-7): ~half the
// instruction count of device-lib erff. exp in exp2 domain.
__device__ __forceinline__ float gelu_f(float v) {
    const float ax = fabsf(v) * 0.70710678118f;           // |x|/sqrt(2)
    const float t  = __builtin_amdgcn_rcpf(fmaf(0.3275911f, ax, 1.f));
    float p = fmaf(1.061405429f, t, -1.453152027f);
    p = fmaf(p, t, 1.421413741f);
    p = fmaf(p, t, -0.284496736f);
    p = fmaf(p, t, 0.254829592f);
    p *= t;
    const float e = __builtin_amdgcn_exp2f(ax * ax * -1.4426950408889634f);
    float erfv = fmaf(-p, e, 1.f);
    erfv = copysignf(erfv, v);
    return 0.5f * v * (1.f + erfv);
}

// ---------------------------------------------------------------------------
// 3-buffer counted-vmcnt GEMM core (T3+T4): per K-step issue stage t+2,
// ds_read+MFMA tile t, then s_waitcnt vmcnt(4) (stage t+1 complete, t+2 still
// in flight) + raw s_barrier. Never vmcnt(0) in the steady-state loop.
// Safety: each wave proves ITS OWN t+1 loads done before the barrier; barrier
// arrival of all waves => all of buf[t+1] complete. WAR on recycled buffers is
// ordered because ds_reads retire before the MFMAs that precede the barrier.
// ---------------------------------------------------------------------------
__device__ __forceinline__ void stage4(const u16* gA, const u16* gB,
                                       u16* lA, u16* lB, int w, int K) {
    async_copy16(gA, lA + w * 512);
    async_copy16(gA + (size_t)64 * K, lA + w * 512 + 2048);
    async_copy16(gB, lB + w * 512);
    async_copy16(gB + (size_t)64 * K, lB + w * 512 + 2048);
}

__device__ __forceinline__ void gemm_core(
    const u16* gA, const u16* gB, int K, int nk,
    u16 (&As)[3][128 * 32], u16 (&Bs)[3][128 * 32],
    int w, int wm, int wn, int lm, int quad, floatx4 (&acc)[4][4])
{
    // prologue: stages 0 and 1
    stage4(gA, gB, As[0], Bs[0], w, K); gA += 32; gB += 32;
    stage4(gA, gB, As[1], Bs[1], w, K); gA += 32; gB += 32;
    asm volatile("s_waitcnt vmcnt(4)" ::: "memory");   // stage 0 done
    __builtin_amdgcn_s_barrier();

    int cur = 0, stg = 2;
    for (int t = 0; t < nk; ++t) {
        if (t + 2 < nk) {
            stage4(gA, gB, As[stg], Bs[stg], w, K);
            gA += 32; gB += 32;
        }
        const u16* Ac = As[cur];
        const u16* Bc = Bs[cur];
        short8 af[4], bfr[4];
#pragma unroll
        for (int t4 = 0; t4 < 4; ++t4)
            af[t4] = *(const short8*)&Ac[(wm * 64 + t4 * 16 + lm) * 32 + quad * 8];
#pragma unroll
        for (int t4 = 0; t4 < 4; ++t4)
            bfr[t4] = *(const short8*)&Bc[(wn * 64 + t4 * 16 + lm) * 32 + quad * 8];
#pragma unroll
        for (int i = 0; i < 4; ++i)
#pragma unroll
            for (int j = 0; j < 4; ++j)
                acc[i][j] = __builtin_amdgcn_mfma_f32_16x16x32_bf16(
                    af[i], bfr[j], acc[i][j], 0, 0, 0);

        if (t + 2 < nk)      asm volatile("s_waitcnt vmcnt(4)" ::: "memory");
        else if (t + 1 < nk) asm volatile("s_waitcnt vmcnt(0)" ::: "memory");
        if (t + 1 < nk) __builtin_amdgcn_s_barrier();
        cur = (cur == 2) ? 0 : cur + 1;
        stg = (stg == 2) ? 0 : stg + 1;
    }
}

// ---------------------------------------------------------------------------
// f32 -> bf16 elementwise convert (x). n multiple of 1024.
// ---------------------------------------------------------------------------
__global__ __launch_bounds__(256) void cvt_f32_bf16(
    const float* __restrict__ in, u16* __restrict__ out, int n)
{
    const int i = (blockIdx.x * 256 + threadIdx.x) * 4;
    if (i < n) {
        const float4 v = *(const float4*)(in + i);
        out[i + 0] = f2bf(v.x);
        out[i + 1] = f2bf(v.y);
        out[i + 2] = f2bf(v.z);
        out[i + 3] = f2bf(v.w);
    }
}

// ---------------------------------------------------------------------------
// mask (int32) -> additive bias: 0 or -1e30
// ---------------------------------------------------------------------------
__global__ __launch_bounds__(256) void mask_bias(
    const int* __restrict__ mask, float* __restrict__ bias, int n)
{
    const int i = blockIdx.x * 256 + threadIdx.x;
    if (i < n) bias[i] = mask[i] ? 0.f : -1e30f;
}

// ---------------------------------------------------------------------------
// transpose+convert: in f32 (R x C) -> out bf16 (C x R)
// ---------------------------------------------------------------------------
__global__ void transpose_cvt(const float* __restrict__ in, u16* __restrict__ out,
                              int R, int C) {
    __shared__ float t[32][33];
    const int bx = blockIdx.x * 32, by = blockIdx.y * 32;
    const int tx = threadIdx.x, ty = threadIdx.y;
#pragma unroll
    for (int i = 0; i < 32; i += 8)
        t[ty + i][tx] = in[(size_t)(by + ty + i) * C + bx + tx];
    __syncthreads();
#pragma unroll
    for (int i = 0; i < 32; i += 8)
        out[(size_t)(bx + ty + i) * R + by + tx] = f2bf(t[tx][ty + i]);
}

// Fused transpose of the four D x D weights (WQ,WK,WV -> Wqkvt; WY -> WYt).
__global__ void transpose_cvt4(
    const float* __restrict__ WQ, const float* __restrict__ WK,
    const float* __restrict__ WV, const float* __restrict__ WY,
    u16* __restrict__ Wqkvt, u16* __restrict__ WYt)
{
    __shared__ float t[32][33];
    const int zz = blockIdx.z;
    const float* in = zz == 0 ? WQ : zz == 1 ? WK : zz == 2 ? WV : WY;
    u16* out = zz < 3 ? Wqkvt + (size_t)zz * D_ * D_ : WYt;
    const int bx = blockIdx.x * 32, by = blockIdx.y * 32;
    const int tx = threadIdx.x, ty = threadIdx.y;
#pragma unroll
    for (int i = 0; i < 32; i += 8)
        t[ty + i][tx] = in[(size_t)(by + ty + i) * D_ + bx + tx];
    __syncthreads();
#pragma unroll
    for (int i = 0; i < 32; i += 8)
        out[(size_t)(bx + ty + i) * D_ + by + tx] = f2bf(t[tx][ty + i]);
}

// ---------------------------------------------------------------------------
// Generic GEMM: C(MxN) = A(MxK) @ W + bias; W as Wt (NxK bf16), bias f32.
// 128x128 tile, BK=32, 4 waves, mfma 16x16x32 bf16. 3-buf counted-vmcnt loop.
// ---------------------------------------------------------------------------
template<bool GELU, bool OUT_F32>
__global__ __launch_bounds__(256) void gemm_bt(
    const u16* __restrict__ A, const u16* __restrict__ Bt,
    const float* __restrict__ bias, void* __restrict__ Cout,
    int M, int N, int K)
{
    __shared__ alignas(16) u16 As[3][128 * 32];
    __shared__ alignas(16) u16 Bs[3][128 * 32];
    const int tid = threadIdx.x;
    const int w = tid >> 6, lane = tid & 63;
    const int lm = lane & 15, quad = lane >> 4;
    const int wm = w >> 1, wn = w & 1;

    const int nwg = gridDim.x * gridDim.y;
    int bid = blockIdx.y * gridDim.x + blockIdx.x;
    if ((nwg & 7) == 0) {
        const int cpx = nwg >> 3;
        bid = (bid & 7) * cpx + (bid >> 3);
    }
    const int bx = bid % gridDim.x, by = bid / gridDim.x;
    const size_t m0 = (size_t)by * 128, n0 = (size_t)bx * 128;

    const int rowS = w * 16 + (lane >> 2);
    const int colS = (lane & 3) * 8;
    const u16* gA = A + (m0 + rowS) * K + colS;
    const u16* gB = Bt + (n0 + rowS) * K + colS;

    floatx4 acc[4][4];
    const floatx4 z = {0.f, 0.f, 0.f, 0.f};
#pragma unroll
    for (int i = 0; i < 4; ++i)
#pragma unroll
        for (int j = 0; j < 4; ++j) acc[i][j] = z;

    gemm_core(gA, gB, K, K >> 5, As, Bs, w, wm, wn, lm, quad, acc);

#pragma unroll
    for (int i = 0; i < 4; ++i) {
        const size_t r0 = m0 + wm * 64 + i * 16 + quad * 4;
#pragma unroll
        for (int j = 0; j < 4; ++j) {
            const size_t c = n0 + wn * 64 + j * 16 + lm;
            const float bv = bias[c];
#pragma unroll
            for (int t = 0; t < 4; ++t) {
                float v = acc[i][j][t] + bv;
                if (GELU) v = gelu_f(v);
                if (OUT_F32) ((float*)Cout)[(r0 + t) * (size_t)N + c] = v;
                else         ((u16*)Cout)[(r0 + t) * (size_t)N + c] = f2bf(v);
            }
        }
    }
}

// ---------------------------------------------------------------------------
// Split-K GEMM with PARTIAL STORES (no atomics). gridDim.z = nsplit.
// kh==0 writes out0 (+bias); kh>0 writes Pext + (kh-1)*M*N.
// ---------------------------------------------------------------------------
__global__ __launch_bounds__(256) void gemm_bt_skp(
    const u16* __restrict__ A, const u16* __restrict__ Bt,
    const float* __restrict__ bias, float* __restrict__ out0,
    float* __restrict__ Pext, int M, int N, int K)
{
    __shared__ alignas(16) u16 As[3][128 * 32];
    __shared__ alignas(16) u16 Bs[3][128 * 32];
    const int tid = threadIdx.x;
    const int w = tid >> 6, lane = tid & 63;
    const int lm = lane & 15, quad = lane >> 4;
    const int wm = w >> 1, wn = w & 1;
    const int kh = blockIdx.z;
    const int Ks = K / gridDim.z;

    const int nwg = gridDim.x * gridDim.y;
    int bid = blockIdx.y * gridDim.x + blockIdx.x;
    if ((nwg & 7) == 0) {
        const int cpx = nwg >> 3;
        bid = (bid & 7) * cpx + (bid >> 3);
    }
    const int bx = bid % gridDim.x, by = bid / gridDim.x;
    const size_t m0 = (size_t)by * 128, n0 = (size_t)bx * 128;

    const int rowS = w * 16 + (lane >> 2);
    const int colS = (lane & 3) * 8;
    const u16* gA = A + (m0 + rowS) * K + (size_t)kh * Ks + colS;
    const u16* gB = Bt + (n0 + rowS) * K + (size_t)kh * Ks + colS;

    floatx4 acc[4][4];
    const floatx4 z = {0.f, 0.f, 0.f, 0.f};
#pragma unroll
    for (int i = 0; i < 4; ++i)
#pragma unroll
        for (int j = 0; j < 4; ++j) acc[i][j] = z;

    gemm_core(gA, gB, K, Ks >> 5, As, Bs, w, wm, wn, lm, quad, acc);

    float* Cout = (kh == 0) ? out0 : Pext + (size_t)(kh - 1) * ((size_t)M * N);
#pragma unroll
    for (int i = 0; i < 4; ++i) {
        const size_t r0 = m0 + wm * 64 + i * 16 + quad * 4;
#pragma unroll
        for (int j = 0; j < 4; ++j) {
            const size_t c = n0 + wn * 64 + j * 16 + lm;
            const float bv = (kh == 0) ? bias[c] : 0.f;
#pragma unroll
            for (int t = 0; t < 4; ++t)
                Cout[(r0 + t) * (size_t)N + c] = acc[i][j][t] + bv;
        }
    }
}

// ---------------------------------------------------------------------------
// Fallback: split-K=2 GEMM, atomic f32 accumulate (used when ws too small).
// ---------------------------------------------------------------------------
__global__ __launch_bounds__(256) void gemm_bt_sk2(
    const u16* __restrict__ A, const u16* __restrict__ Bt,
    const float* __restrict__ bias, float* __restrict__ Cout,
    int M, int N, int K)
{
    __shared__ alignas(16) u16 As[3][128 * 32];
    __shared__ alignas(16) u16 Bs[3][128 * 32];
    const int tid = threadIdx.x;
    const int w = tid >> 6, lane = tid & 63;
    const int lm = lane & 15, quad = lane >> 4;
    const int wm = w >> 1, wn = w & 1;
    const int kh = blockIdx.z;
    const int Ks = K >> 1;
    const size_t m0 = (size_t)blockIdx.y * 128, n0 = (size_t)blockIdx.x * 128;

    const int rowS = w * 16 + (lane >> 2);
    const int colS = (lane & 3) * 8;
    const u16* gA = A + (m0 + rowS) * K + (size_t)kh * Ks + colS;
    const u16* gB = Bt + (n0 + rowS) * K + (size_t)kh * Ks + colS;

    floatx4 acc[4][4];
    const floatx4 z = {0.f, 0.f, 0.f, 0.f};
#pragma unroll
    for (int i = 0; i < 4; ++i)
#pragma unroll
        for (int j = 0; j < 4; ++j) acc[i][j] = z;

    gemm_core(gA, gB, K, Ks >> 5, As, Bs, w, wm, wn, lm, quad, acc);

#pragma unroll
    for (int i = 0; i < 4; ++i) {
        const size_t r0 = m0 + wm * 64 + i * 16 + quad * 4;
#pragma unroll
        for (int j = 0; j < 4; ++j) {
            const size_t c = n0 + wn * 64 + j * 16 + lm;
            const float bv = (kh == 0) ? bias[c] : 0.f;
#pragma unroll
            for (int t = 0; t < 4; ++t)
                atomicAdd(&Cout[(r0 + t) * (size_t)N + c], acc[i][j][t] + bv);
        }
    }
}

// ---------------------------------------------------------------------------
// Fused QKV GEMM: A(M x 1024) @ Wqkv (1024 x 3072), Wqkvt rows: [WQ^T;WK^T;WV^T].
// Q,K written [m][1024]; V written transposed per head: Vt[((b*16+h)*64+dh)*S + s].
// ---------------------------------------------------------------------------
__global__ __launch_bounds__(256) void gemm_qkv(
    const u16* __restrict__ A, const u16* __restrict__ Bt,
    const float* __restrict__ bQ, const float* __restrict__ bK,
    const float* __restrict__ bV,
    u16* __restrict__ Qb, u16* __restrict__ Kb, u16* __restrict__ Vt)
{
    const int K = D_;
    __shared__ alignas(16) u16 As[3][128 * 32];
    __shared__ alignas(16) u16 Bs[3][128 * 32];
    const int tid = threadIdx.x;
    const int w = tid >> 6, lane = tid & 63;
    const int lm = lane & 15, quad = lane >> 4;
    const int wm = w >> 1, wn = w & 1;

    const int nwg = gridDim.x * gridDim.y;
    int bid = blockIdx.y * gridDim.x + blockIdx.x;
    if ((nwg & 7) == 0) {
        const int cpx = nwg >> 3;
        bid = (bid & 7) * cpx + (bid >> 3);
    }
    const int bx = bid % gridDim.x, by = bid / gridDim.x;
    const size_t m0 = (size_t)by * 128, n0 = (size_t)bx * 128;

    const int rowS = w * 16 + (lane >> 2);
    const int colS = (lane & 3) * 8;
    const u16* gA = A + (m0 + rowS) * K + colS;
    const u16* gB = Bt + (n0 + rowS) * K + colS;

    floatx4 acc[4][4];
    const floatx4 z = {0.f, 0.f, 0.f, 0.f};
#pragma unroll
    for (int i = 0; i < 4; ++i)
#pragma unroll
        for (int j = 0; j < 4; ++j) acc[i][j] = z;

    gemm_core(gA, gB, K, K >> 5, As, Bs, w, wm, wn, lm, quad, acc);

#pragma unroll
    for (int i = 0; i < 4; ++i) {
        const size_t r0 = m0 + wm * 64 + i * 16 + quad * 4;
#pragma unroll
        for (int j = 0; j < 4; ++j) {
            const size_t c = n0 + wn * 64 + j * 16 + lm;
            const int sel = (int)(c >> 10);       // 0=Q 1=K 2=V (uniform per j)
            const int col = (int)(c & 1023);
            const float bv = sel == 0 ? bQ[col] : (sel == 1 ? bK[col] : bV[col]);
#pragma unroll
            for (int t = 0; t < 4; ++t) {
                const size_t r = r0 + t;
                const u16 v = f2bf(acc[i][j][t] + bv);
                if (sel == 0)      Qb[r * (size_t)D_ + col] = v;
                else if (sel == 1) Kb[r * (size_t)D_ + col] = v;
                else {
                    const int h = col >> 6, dh = col & 63;
                    const int bb = (int)(r >> 11), s = (int)(r & 2047);
                    Vt[((size_t)((bb * 16 + h) * 64 + dh)) * S_ + s] = v;
                }
            }
        }
    }
}

// ---------------------------------------------------------------------------
// Flash attention, S^T formulation: grid (S/64, B*H); 4 waves x 16 queries.
// exp2-domain softmax, cvt_pk bf16 packing, defer-max rescale, dbuf LDS,
// tree-structured max and sum reductions (short dependent chains).
// ---------------------------------------------------------------------------
__global__ __launch_bounds__(256) void attn_kernel(
    const u16* __restrict__ Q, const u16* __restrict__ Kg,
    const u16* __restrict__ Vt, const float* __restrict__ mbias,
    u16* __restrict__ O)
{
    __shared__ alignas(16) u16 Kt[2][64 * 72];
    __shared__ alignas(16) u16 Vs[2][64 * 72];   // [dh][key]
    const int tid = threadIdx.x, w = tid >> 6, lane = tid & 63;
    const int lm = lane & 15, quad = lane >> 4;
    const int b = blockIdx.y >> 4, h = blockIdx.y & 15;
    const int q0 = blockIdx.x * 64;

    // Q B-frag: n = lane&15 -> query, k = quad*8+j -> dh
    const u16* qp = Q + ((size_t)(b * S_ + q0 + w * 16 + lm)) * D_ + h * 64;
    const short8 bq0 = *(const short8*)(qp + quad * 8);
    const short8 bq1 = *(const short8*)(qp + 32 + quad * 8);

    // staging: thread covers row tid>>2 (0..63), 16 u16 at col (tid&3)*16
    const int sRow = tid >> 2, sCol = (tid & 3) * 16;
    const u16* gK = Kg + ((size_t)(b * S_ + sRow)) * D_ + h * 64 + sCol;
    const u16* gV = Vt + ((size_t)((b * 16 + h) * 64 + sRow)) * S_ + sCol;

    float mrow = -1e30f, lrow = 0.f;
    floatx4 o[4];                                // o[dhs][reg], O^T layout
    const floatx4 z = {0.f, 0.f, 0.f, 0.f};
#pragma unroll
    for (int i = 0; i < 4; ++i) o[i] = z;

    const float* bp = mbias + b * S_;
    const float SCL = 0.18033688011112042f;      // 0.125 * log2(e)

    // prologue: tile 0 into registers
    short8 rk0 = *(const short8*)(gK);
    short8 rk1 = *(const short8*)(gK + 8);
    short8 rv0 = *(const short8*)(gV);
    short8 rv1 = *(const short8*)(gV + 8);

    for (int it = 0; it < NT_; ++it) {
        u16* kb = Kt[it & 1];
        u16* vb = Vs[it & 1];
        *(short8*)&kb[sRow * 72 + sCol]     = rk0;
        *(short8*)&kb[sRow * 72 + sCol + 8] = rk1;
        *(short8*)&vb[sRow * 72 + sCol]     = rv0;
        *(short8*)&vb[sRow * 72 + sCol + 8] = rv1;
        __syncthreads();
        if (it + 1 < NT_) {                      // issue next tile under compute
            gK += (size_t)64 * D_; gV += 64;
            rk0 = *(const short8*)(gK);
            rk1 = *(const short8*)(gK + 8);
            rv0 = *(const short8*)(gV);
            rv1 = *(const short8*)(gV + 8);
        }

        // S^T (64 keys x 16 queries): A = K-frag, B = Q-frag
        floatx4 st[4];
        __builtin_amdgcn_s_setprio(1);
#pragma unroll
        for (int ks = 0; ks < 4; ++ks) {
            floatx4 s = z;
            const short8 ak0 = *(const short8*)&kb[(ks * 16 + lm) * 72 + quad * 8];
            const short8 ak1 = *(const short8*)&kb[(ks * 16 + lm) * 72 + 32 + quad * 8];
            s = __builtin_amdgcn_mfma_f32_16x16x32_bf16(ak0, bq0, s, 0, 0, 0);
            s = __builtin_amdgcn_mfma_f32_16x16x32_bf16(ak1, bq1, s, 0, 0, 0);
            const float4 mb4 = *(const float4*)&bp[it * 64 + ks * 16 + quad * 4];
            st[ks][0] = fmaf(s[0], SCL, mb4.x);
            st[ks][1] = fmaf(s[1], SCL, mb4.y);
            st[ks][2] = fmaf(s[2], SCL, mb4.z);
            st[ks][3] = fmaf(s[3], SCL, mb4.w);
        }
        __builtin_amdgcn_s_setprio(0);

        // tile max: balanced tree, then cross-quad (xor 16, 32)
        float m01 = fmaxf(fmaxf(st[0][0], st[0][1]), fmaxf(st[0][2], st[0][3]));
        float m11 = fmaxf(fmaxf(st[1][0], st[1][1]), fmaxf(st[1][2], st[1][3]));
        float m21 = fmaxf(fmaxf(st[2][0], st[2][1]), fmaxf(st[2][2], st[2][3]));
        float m31 = fmaxf(fmaxf(st[3][0], st[3][1]), fmaxf(st[3][2], st[3][3]));
        float tm = fmaxf(fmaxf(m01, m11), fmaxf(m21, m31));
        tm = fmaxf(tm, __shfl_xor(tm, 16));
        tm = fmaxf(tm, __shfl_xor(tm, 32));

        // defer-max: only rescale when the running max grew by > 8 (log2)
        if (!__all(tm <= mrow + 8.f)) {
            const float mn = fmaxf(mrow, tm);
            const float al = __builtin_amdgcn_exp2f(mrow - mn);
            mrow = mn;
            lrow *= al;
#pragma unroll
            for (int d = 0; d < 4; ++d) o[d] *= al;
        }

        // exp2 + tree sum (depth-4 dependent chain instead of 16)
        float sks[4];
#pragma unroll
        for (int ks = 0; ks < 4; ++ks) {
#pragma unroll
            for (int r = 0; r < 4; ++r)
                st[ks][r] = __builtin_amdgcn_exp2f(st[ks][r] - mrow);
            sks[ks] = (st[ks][0] + st[ks][1]) + (st[ks][2] + st[ks][3]);
        }
        float rs = (sks[0] + sks[1]) + (sks[2] + sks[3]);
        rs += __shfl_xor(rs, 16);
        rs += __shfl_xor(rs, 32);
        lrow += rs;

        // P^T B-frags for 16x16x16: k = quad*4+j (key), n = lm (query)
        short4v pb[4];
#pragma unroll
        for (int ks = 0; ks < 4; ++ks) {
            uint2 uu;
            uu.x = cvtpk_bf16(st[ks][0], st[ks][1]);
            uu.y = cvtpk_bf16(st[ks][2], st[ks][3]);
            pb[ks] = __builtin_bit_cast(short4v, uu);
        }
        // O^T += V^T · P^T ; V^T A-frag: m=dh (lm), k=key=quad*4+j (b64 read)
        __builtin_amdgcn_s_setprio(1);
#pragma unroll
        for (int d = 0; d < 4; ++d)
#pragma unroll
            for (int ks = 0; ks < 4; ++ks) {
                const short4v av = *(const short4v*)&vb[(d * 16 + lm) * 72 + ks * 16 + quad * 4];
                o[d] = __builtin_amdgcn_mfma_f32_16x16x16bf16_1k(av, pb[ks], o[d], 0, 0, 0);
            }
        __builtin_amdgcn_s_setprio(0);
    }
    // O^T C-layout: row=dh=quad*4+reg, col=query=lm -> 4 contiguous u16/store
    const float inv = __builtin_amdgcn_rcpf(lrow);
    u16* op = O + ((size_t)(b * S_ + q0 + w * 16 + lm)) * D_ + h * 64 + quad * 4;
#pragma unroll
    for (int d = 0; d < 4; ++d) {
        uint2 uu;
        uu.x = cvtpk_bf16(o[d][0] * inv, o[d][1] * inv);
        uu.y = cvtpk_bf16(o[d][2] * inv, o[d][3] * inv);
        *(uint2*)(op + d * 16) = uu;
    }
}

// ---------------------------------------------------------------------------
// out = LayerNorm(mainp + resid) * gamma + beta. (fallback, no partials)
// ---------------------------------------------------------------------------
template<bool MAIN_F32, bool RESID_F32, bool OUT_F32>
__global__ __launch_bounds__(256) void add_ln(
    const void* __restrict__ mainp, const void* __restrict__ resid,
    const float* __restrict__ gamma, const float* __restrict__ beta,
    void* __restrict__ out)
{
    const int row = blockIdx.x;
    const size_t base = (size_t)row * D_;
    const int t = threadIdx.x;
    const int w = t >> 6, lane = t & 63;
    float v[4];
#pragma unroll
    for (int i = 0; i < 4; ++i) {
        const int c = i * 256 + t;
        const float mv = MAIN_F32 ? ((const float*)mainp)[base + c]
                                  : bf2f(((const u16*)mainp)[base + c]);
        const float rv = RESID_F32 ? ((const float*)resid)[base + c]
                                   : bf2f(((const u16*)resid)[base + c]);
        v[i] = mv + rv;
    }
    float s = v[0] + v[1] + v[2] + v[3];
#pragma unroll
    for (int off = 32; off >= 1; off >>= 1) s += __shfl_xor(s, off);
    __shared__ float red[8];
    if (lane == 0) red[w] = s;
    __syncthreads();
    const float mean = (red[0] + red[1] + red[2] + red[3]) * (1.0f / D_);
    float q = 0.f;
#pragma unroll
    for (int i = 0; i < 4; ++i) { const float dd = v[i] - mean; q += dd * dd; }
#pragma unroll
    for (int off = 32; off >= 1; off >>= 1) q += __shfl_xor(q, off);
    if (lane == 0) red[4 + w] = q;
    __syncthreads();
    const float var = (red[4] + red[5] + red[6] + red[7]) * (1.0f / D_);
    const float rstd = rsqrtf(var + 1e-5f);
#pragma unroll
    for (int i = 0; i < 4; ++i) {
        const int c = i * 256 + t;
        const float o = (v[i] - mean) * rstd * gamma[c] + beta[c];
        if (OUT_F32) ((float*)out)[base + c] = o;
        else         ((u16*)out)[base + c] = f2bf(o);
    }
}

// ---------------------------------------------------------------------------
// out = LayerNorm(mainp + sum(Pext partials) + resid) * gamma + beta.
// Fused split-K reduction + add + LN. All partials f32.
// ---------------------------------------------------------------------------
template<int NEXT, bool RESID_F32, bool OUT_F32>
__global__ __launch_bounds__(256) void add_ln_red(
    const float* __restrict__ mainp, const float* __restrict__ Pext,
    const void* __restrict__ resid,
    const float* __restrict__ gamma, const float* __restrict__ beta,
    void* __restrict__ out)
{
    const int row = blockIdx.x;
    const size_t base = (size_t)row * D_;
    const int t = threadIdx.x;
    const int w = t >> 6, lane = t & 63;
    float v[4];
#pragma unroll
    for (int i = 0; i < 4; ++i) {
        const int c = i * 256 + t;
        float s = mainp[base + c];
#pragma unroll
        for (int p = 0; p < NEXT; ++p)
            s += Pext[(size_t)p * ((size_t)M_ * D_) + base + c];
        s += RESID_F32 ? ((const float*)resid)[base + c]
                       : bf2f(((const u16*)resid)[base + c]);
        v[i] = s;
    }
    float s = v[0] + v[1] + v[2] + v[3];
#pragma unroll
    for (int off = 32; off >= 1; off >>= 1) s += __shfl_xor(s, off);
    __shared__ float red[8];
    if (lane == 0) red[w] = s;
    __syncthreads();
    const float mean = (red[0] + red[1] + red[2] + red[3]) * (1.0f / D_);
    float q = 0.f;
#pragma unroll
    for (int i = 0; i < 4; ++i) { const float dd = v[i] - mean; q += dd * dd; }
#pragma unroll
    for (int off = 32; off >= 1; off >>= 1) q += __shfl_xor(q, off);
    if (lane == 0) red[4 + w] = q;
    __syncthreads();
    const float var = (red[4] + red[5] + red[6] + red[7]) * (1.0f / D_);
    const float rstd = rsqrtf(var + 1e-5f);
#pragma unroll
    for (int i = 0; i < 4; ++i) {
        const int c = i * 256 + t;
        const float o = (v[i] - mean) * rstd * gamma[c] + beta[c];
        if (OUT_F32) ((float*)out)[base + c] = o;
        else         ((u16*)out)[base + c] = f2bf(o);
    }
}

// ---------------------------------------------------------------------------
extern "C" void kernel_launch(void* const* d_in, const int* in_sizes, int n_in,
                              void* d_out, int out_size, void* d_ws, size_t ws_size,
                              hipStream_t stream)
{
    const float* x   = (const float*)d_in[0];
    const int* mask  = (const int*)d_in[1];
    const float* WQ = (const float*)d_in[2];  const float* bQ = (const float*)d_in[3];
    const float* WK = (const float*)d_in[4];  const float* bK = (const float*)d_in[5];
    const float* WV = (const float*)d_in[6];  const float* bV = (const float*)d_in[7];
    const float* WY = (const float*)d_in[8];  const float* bY = (const float*)d_in[9];
    const float* ln1w = (const float*)d_in[10]; const float* ln1b = (const float*)d_in[11];
    const float* ln2w = (const float*)d_in[12]; const float* ln2b = (const float*)d_in[13];
    const float* W1 = (const float*)d_in[14]; const float* b1 = (const float*)d_in[15];
    const float* W2 = (const float*)d_in[16]; const float* b2 = (const float*)d_in[17];

    // Workspace:
    //  [0,8)  xb -> W1t -> W2t
    //  [8,14) Wqkvt, [14,16) WYt -> hbf [8,16)
    //  [16,24) Qb, [24,32) Kb -> Ypf [16,32) -> G [16,48)
    //  [32,40) Vt, [40,48) Yat -> G
    //  [48, +16KB) mask bias
    //  [49, 49+16) split-K partial buffer (gated on ws_size)
    char* ws = (char*)d_ws;
    u16* xb    = (u16*)(ws + 0  * MB_);
    u16* Wqkvt = (u16*)(ws + 8  * MB_);        // 6 MB: [WQ^T; WK^T; WV^T]
    u16* WYt   = (u16*)(ws + 14 * MB_);        // 2 MB
    u16* Qb    = (u16*)(ws + 16 * MB_);
    u16* Kb    = (u16*)(ws + 24 * MB_);
    u16* Vt    = (u16*)(ws + 32 * MB_);        // [b][h][dh][s]
    u16* Yat   = (u16*)(ws + 40 * MB_);
    float* Ypf = (float*)(ws + 16 * MB_);      // 16 MB f32, after Qb/Kb dead
    u16* hbf   = (u16*)(ws + 8  * MB_);        // after Wqkvt/WYt dead
    u16* W1t   = (u16*)(ws + 0  * MB_);        // after xb dead
    u16* G     = (u16*)(ws + 16 * MB_);        // after Ypf/Vt/Yat dead
    u16* W2t   = (u16*)(ws + 0  * MB_);        // after W1t dead
    float* mb  = (float*)(ws + 48 * MB_);      // 16 KB mask bias
    float* Pext = (float*)(ws + 49 * MB_);     // split-K partial (f32)

    const size_t PART = (size_t)M_ * D_ * sizeof(float);          // 16 MB
    const bool ws1 = ws_size >= 49 * MB_ + 1 * PART;              // >= 65 MB

    const dim3 tb(32, 8);

    cvt_f32_bf16<<<(M_*D_)/1024, 256, 0, stream>>>(x, xb, M_*D_);
    mask_bias<<<(B_*S_)/256, 256, 0, stream>>>(mask, mb, B_*S_);
    transpose_cvt4<<<dim3(D_/32, D_/32, 4), tb, 0, stream>>>(WQ, WK, WV, WY, Wqkvt, WYt);

    gemm_qkv<<<dim3(3*D_/128, M_/128), 256, 0, stream>>>(xb, Wqkvt, bQ, bK, bV, Qb, Kb, Vt);

    attn_kernel<<<dim3(S_/64, B_*H_), 256, 0, stream>>>(Qb, Kb, Vt, mb, Yat);

    // ---- Y-proj (N=1024): split-K=2 partial stores ----
    if (ws1) {
        gemm_bt_skp<<<dim3(D_/128, M_/128, 2), 256, 0, stream>>>(
            Yat, WYt, bY, Ypf, Pext, M_, D_, D_);
        add_ln_red<1,true,false><<<M_, 256, 0, stream>>>(Ypf, Pext, x, ln1w, ln1b, hbf);
    } else {
        hipMemsetAsync(Ypf, 0, PART, stream);
        gemm_bt_sk2<<<dim3(D_/128, M_/128, 2), 256, 0, stream>>>(
            Yat, WYt, bY, Ypf, M_, D_, D_);
        add_ln<true,true,false><<<M_, 256, 0, stream>>>(Ypf, x, ln1w, ln1b, hbf);
    }

    transpose_cvt<<<dim3(FF_/32, D_/32), tb, 0, stream>>>(W1, W1t, D_, FF_);
    gemm_bt<true,false><<<dim3(FF_/128, M_/128), 256, 0, stream>>>(hbf, W1t, b1, G, M_, FF_, D_);

    transpose_cvt<<<dim3(D_/32, FF_/32), tb, 0, stream>>>(W2, W2t, FF_, D_);

    // ---- FF2 (N=1024, K=4096): split-K=2 partial stores ----
    if (ws1) {
        gemm_bt_skp<<<dim3(D_/128, M_/128, 2), 256, 0, stream>>>(
            G, W2t, b2, (float*)d_out, Pext, M_, D_, FF_);
        add_ln_red<1,false,true><<<M_, 256, 0, stream>>>(
            (float*)d_out, Pext, hbf, ln2w, ln2b, d_out);
    } else {
        hipMemsetAsync(d_out, 0, (size_t)M_ * D_ * 4, stream);
        gemm_bt_sk2<<<dim3(D_/128, M_/128, 2), 256, 0, stream>>>(
            G, W2t, b2, (float*)d_out, M_, D_, FF_);
        add_ln<true,false,true><<<M_, 256, 0, stream>>>(
            (float*)d_out, hbf, ln2w, ln2b, d_out);
    }
}

// Round 5
// 399.576 us; speedup vs baseline: 1.2524x; 1.0146x over previous
//
#include <hip/hip_runtime.h>
#include <cstdint>
#include <cstddef>

#define B_ 2
#define S_ 2048
#define D_ 1024
#define H_ 16
#define DH_ 64
#define FF_ 4096
#define M_ (B_*S_)
#define MB_ ((size_t)1 << 20)
#define NT_ (S_/64)

using u16 = unsigned short;
using u64 = unsigned long long;
using short8 = __attribute__((ext_vector_type(8))) short;
using short4v = __attribute__((ext_vector_type(4))) short;
using floatx4 = __attribute__((ext_vector_type(4))) float;
using u64x2 = __attribute__((ext_vector_type(2))) unsigned long long;

__device__ __forceinline__ float bf2f(u16 u) {
    return __uint_as_float(((uint32_t)u) << 16);
}
__device__ __forceinline__ u16 f2bf(float f) {
    uint32_t u = __float_as_uint(f);
    u += 0x7fffu + ((u >> 16) & 1u);   // RNE
    return (u16)(u >> 16);
}
// pack two f32 -> bf16x2 in one VALU op (RNE)
__device__ __forceinline__ uint32_t cvtpk_bf16(float lo, float hi) {
    uint32_t r;
    asm("v_cvt_pk_bf16_f32 %0, %1, %2" : "=v"(r) : "v"(lo), "v"(hi));
    return r;
}
// async global->LDS, 16B per lane; LDS dest = wave-uniform base + lane*16
__device__ __forceinline__ void async_copy16(const u16* g, u16* l) {
    __builtin_amdgcn_global_load_lds(
        (const __attribute__((address_space(1))) uint32_t*)g,
        (__attribute__((address_space(3))) uint32_t*)l, 16, 0, 0);
}

// GELU via Abramowitz-Stegun 7.1.26 erf (|eps| <= 1.5e-7).
__device__ __forceinline__ float gelu_f(float v) {
    const float ax = fabsf(v) * 0.70710678118f;           // |x|/sqrt(2)
    const float t  = __builtin_amdgcn_rcpf(fmaf(0.3275911f, ax, 1.f));
    float p = fmaf(1.061405429f, t, -1.453152027f);
    p = fmaf(p, t, 1.421413741f);
    p = fmaf(p, t, -0.284496736f);
    p = fmaf(p, t, 0.254829592f);
    p *= t;
    const float e = __builtin_amdgcn_exp2f(ax * ax * -1.4426950408889634f);
    float erfv = fmaf(-p, e, 1.f);
    erfv = copysignf(erfv, v);
    return 0.5f * v * (1.f + erfv);
}

// ---------------------------------------------------------------------------
// Bank-conflict-free staging permutation (rule #21: linear LDS dest +
// inverse-permuted GLOBAL source + permuted ds_read).
// Within each wave's 1024B region (16 rows x 64B), 16B block b = r*4+c is
// STORED at position pi(b) = (b&56)|((b+(b>>3))&7). An 8-lane b128 read
// group then hits 8 distinct bank-quads (verified: {0,4,1,5,2,6,3,7}).
// Write side: gload_lds lane l writes position l -> lane must fetch global
// block inv_pi(l) = (l&56)|((l-(l>>3))&7).
// ---------------------------------------------------------------------------
__device__ __forceinline__ int swz_inv(int l) {
    return (l & 56) | ((l - (l >> 3)) & 7);
}
__device__ __forceinline__ int swz_fwd(int b) {
    return (b & 56) | ((b + (b >> 3)) & 7);
}

// ---------------------------------------------------------------------------
// 3-buffer counted-vmcnt GEMM core (T3+T4): per K-step issue stage t+2,
// ds_read+MFMA tile t, then s_waitcnt vmcnt(4) (stage t+1 complete, t+2 still
// in flight) + raw s_barrier. Never vmcnt(0) in the steady-state loop.
// ---------------------------------------------------------------------------
__device__ __forceinline__ void stage4(const u16* gA, const u16* gB,
                                       u16* lA, u16* lB, int w, int K) {
    async_copy16(gA, lA + w * 512);
    async_copy16(gA + (size_t)64 * K, lA + w * 512 + 2048);
    async_copy16(gB, lB + w * 512);
    async_copy16(gB + (size_t)64 * K, lB + w * 512 + 2048);
}

__device__ __forceinline__ void gemm_core(
    const u16* gA, const u16* gB, int K, int nk,
    u16 (&As)[3][128 * 32], u16 (&Bs)[3][128 * 32],
    int w, int wm, int wn, int lm, int quad, floatx4 (&acc)[4][4])
{
    // loop-invariant swizzled read block index (region-relative)
    const int pblk = swz_fwd(lm * 4 + quad);

    // prologue: stages 0 and 1
    stage4(gA, gB, As[0], Bs[0], w, K); gA += 32; gB += 32;
    stage4(gA, gB, As[1], Bs[1], w, K); gA += 32; gB += 32;
    asm volatile("s_waitcnt vmcnt(4)" ::: "memory");   // stage 0 done
    __builtin_amdgcn_s_barrier();

    int cur = 0, stg = 2;
    for (int t = 0; t < nk; ++t) {
        if (t + 2 < nk) {
            stage4(gA, gB, As[stg], Bs[stg], w, K);
            gA += 32; gB += 32;
        }
        const u16* Ac = As[cur];
        const u16* Bc = Bs[cur];
        short8 af[4], bfr[4];
#pragma unroll
        for (int t4 = 0; t4 < 4; ++t4)
            af[t4] = *(const short8*)&Ac[(wm * 4 + t4) * 512 + pblk * 8];
#pragma unroll
        for (int t4 = 0; t4 < 4; ++t4)
            bfr[t4] = *(const short8*)&Bc[(wn * 4 + t4) * 512 + pblk * 8];
#pragma unroll
        for (int i = 0; i < 4; ++i)
#pragma unroll
            for (int j = 0; j < 4; ++j)
                acc[i][j] = __builtin_amdgcn_mfma_f32_16x16x32_bf16(
                    af[i], bfr[j], acc[i][j], 0, 0, 0);

        if (t + 2 < nk)      asm volatile("s_waitcnt vmcnt(4)" ::: "memory");
        else if (t + 1 < nk) asm volatile("s_waitcnt vmcnt(0)" ::: "memory");
        if (t + 1 < nk) __builtin_amdgcn_s_barrier();
        cur = (cur == 2) ? 0 : cur + 1;
        stg = (stg == 2) ? 0 : stg + 1;
    }
}

// ---------------------------------------------------------------------------
// f32 -> bf16 elementwise convert (x). n multiple of 1024.
// ---------------------------------------------------------------------------
__global__ __launch_bounds__(256) void cvt_f32_bf16(
    const float* __restrict__ in, u16* __restrict__ out, int n)
{
    const int i = (blockIdx.x * 256 + threadIdx.x) * 4;
    if (i < n) {
        const float4 v = *(const float4*)(in + i);
        out[i + 0] = f2bf(v.x);
        out[i + 1] = f2bf(v.y);
        out[i + 2] = f2bf(v.z);
        out[i + 3] = f2bf(v.w);
    }
}

// ---------------------------------------------------------------------------
// mask (int32) -> additive bias: 0 or -1e30
// ---------------------------------------------------------------------------
__global__ __launch_bounds__(256) void mask_bias(
    const int* __restrict__ mask, float* __restrict__ bias, int n)
{
    const int i = blockIdx.x * 256 + threadIdx.x;
    if (i < n) bias[i] = mask[i] ? 0.f : -1e30f;
}

// ---------------------------------------------------------------------------
// transpose+convert: in f32 (R x C) -> out bf16 (C x R)
// ---------------------------------------------------------------------------
__global__ void transpose_cvt(const float* __restrict__ in, u16* __restrict__ out,
                              int R, int C) {
    __shared__ float t[32][33];
    const int bx = blockIdx.x * 32, by = blockIdx.y * 32;
    const int tx = threadIdx.x, ty = threadIdx.y;
#pragma unroll
    for (int i = 0; i < 32; i += 8)
        t[ty + i][tx] = in[(size_t)(by + ty + i) * C + bx + tx];
    __syncthreads();
#pragma unroll
    for (int i = 0; i < 32; i += 8)
        out[(size_t)(bx + ty + i) * R + by + tx] = f2bf(t[tx][ty + i]);
}

// Fused transpose of the four D x D weights (WQ,WK,WV -> Wqkvt; WY -> WYt).
__global__ void transpose_cvt4(
    const float* __restrict__ WQ, const float* __restrict__ WK,
    const float* __restrict__ WV, const float* __restrict__ WY,
    u16* __restrict__ Wqkvt, u16* __restrict__ WYt)
{
    __shared__ float t[32][33];
    const int zz = blockIdx.z;
    const float* in = zz == 0 ? WQ : zz == 1 ? WK : zz == 2 ? WV : WY;
    u16* out = zz < 3 ? Wqkvt + (size_t)zz * D_ * D_ : WYt;
    const int bx = blockIdx.x * 32, by = blockIdx.y * 32;
    const int tx = threadIdx.x, ty = threadIdx.y;
#pragma unroll
    for (int i = 0; i < 32; i += 8)
        t[ty + i][tx] = in[(size_t)(by + ty + i) * D_ + bx + tx];
    __syncthreads();
#pragma unroll
    for (int i = 0; i < 32; i += 8)
        out[(size_t)(bx + ty + i) * D_ + by + tx] = f2bf(t[tx][ty + i]);
}

// ---------------------------------------------------------------------------
// Generic GEMM: C(MxN) = A(MxK) @ W + bias; W as Wt (NxK bf16), bias f32.
// 128x128 tile, BK=32, 4 waves, mfma 16x16x32 bf16. 3-buf counted-vmcnt loop.
// ---------------------------------------------------------------------------
template<bool GELU, bool OUT_F32>
__global__ __launch_bounds__(256) void gemm_bt(
    const u16* __restrict__ A, const u16* __restrict__ Bt,
    const float* __restrict__ bias, void* __restrict__ Cout,
    int M, int N, int K)
{
    __shared__ alignas(16) u16 As[3][128 * 32];
    __shared__ alignas(16) u16 Bs[3][128 * 32];
    const int tid = threadIdx.x;
    const int w = tid >> 6, lane = tid & 63;
    const int lm = lane & 15, quad = lane >> 4;
    const int wm = w >> 1, wn = w & 1;

    const int nwg = gridDim.x * gridDim.y;
    int bid = blockIdx.y * gridDim.x + blockIdx.x;
    if ((nwg & 7) == 0) {
        const int cpx = nwg >> 3;
        bid = (bid & 7) * cpx + (bid >> 3);
    }
    const int bx = bid % gridDim.x, by = bid / gridDim.x;
    const size_t m0 = (size_t)by * 128, n0 = (size_t)bx * 128;

    const int bwr = swz_inv(lane);
    const int rowS = w * 16 + (bwr >> 2);
    const int colS = (bwr & 3) * 8;
    const u16* gA = A + (m0 + rowS) * K + colS;
    const u16* gB = Bt + (n0 + rowS) * K + colS;

    floatx4 acc[4][4];
    const floatx4 z = {0.f, 0.f, 0.f, 0.f};
#pragma unroll
    for (int i = 0; i < 4; ++i)
#pragma unroll
        for (int j = 0; j < 4; ++j) acc[i][j] = z;

    gemm_core(gA, gB, K, K >> 5, As, Bs, w, wm, wn, lm, quad, acc);

#pragma unroll
    for (int i = 0; i < 4; ++i) {
        const size_t r0 = m0 + wm * 64 + i * 16 + quad * 4;
#pragma unroll
        for (int j = 0; j < 4; ++j) {
            const size_t c = n0 + wn * 64 + j * 16 + lm;
            const float bv = bias[c];
#pragma unroll
            for (int t = 0; t < 4; ++t) {
                float v = acc[i][j][t] + bv;
                if (GELU) v = gelu_f(v);
                if (OUT_F32) ((float*)Cout)[(r0 + t) * (size_t)N + c] = v;
                else         ((u16*)Cout)[(r0 + t) * (size_t)N + c] = f2bf(v);
            }
        }
    }
}

// ---------------------------------------------------------------------------
// Split-K GEMM with PARTIAL STORES (no atomics). gridDim.z = nsplit.
// kh==0 writes out0 (+bias); kh>0 writes Pext + (kh-1)*M*N.
// ---------------------------------------------------------------------------
__global__ __launch_bounds__(256) void gemm_bt_skp(
    const u16* __restrict__ A, const u16* __restrict__ Bt,
    const float* __restrict__ bias, float* __restrict__ out0,
    float* __restrict__ Pext, int M, int N, int K)
{
    __shared__ alignas(16) u16 As[3][128 * 32];
    __shared__ alignas(16) u16 Bs[3][128 * 32];
    const int tid = threadIdx.x;
    const int w = tid >> 6, lane = tid & 63;
    const int lm = lane & 15, quad = lane >> 4;
    const int wm = w >> 1, wn = w & 1;
    const int kh = blockIdx.z;
    const int Ks = K / gridDim.z;

    const int nwg = gridDim.x * gridDim.y;
    int bid = blockIdx.y * gridDim.x + blockIdx.x;
    if ((nwg & 7) == 0) {
        const int cpx = nwg >> 3;
        bid = (bid & 7) * cpx + (bid >> 3);
    }
    const int bx = bid % gridDim.x, by = bid / gridDim.x;
    const size_t m0 = (size_t)by * 128, n0 = (size_t)bx * 128;

    const int bwr = swz_inv(lane);
    const int rowS = w * 16 + (bwr >> 2);
    const int colS = (bwr & 3) * 8;
    const u16* gA = A + (m0 + rowS) * K + (size_t)kh * Ks + colS;
    const u16* gB = Bt + (n0 + rowS) * K + (size_t)kh * Ks + colS;

    floatx4 acc[4][4];
    const floatx4 z = {0.f, 0.f, 0.f, 0.f};
#pragma unroll
    for (int i = 0; i < 4; ++i)
#pragma unroll
        for (int j = 0; j < 4; ++j) acc[i][j] = z;

    gemm_core(gA, gB, K, Ks >> 5, As, Bs, w, wm, wn, lm, quad, acc);

    float* Cout = (kh == 0) ? out0 : Pext + (size_t)(kh - 1) * ((size_t)M * N);
#pragma unroll
    for (int i = 0; i < 4; ++i) {
        const size_t r0 = m0 + wm * 64 + i * 16 + quad * 4;
#pragma unroll
        for (int j = 0; j < 4; ++j) {
            const size_t c = n0 + wn * 64 + j * 16 + lm;
            const float bv = (kh == 0) ? bias[c] : 0.f;
#pragma unroll
            for (int t = 0; t < 4; ++t)
                Cout[(r0 + t) * (size_t)N + c] = acc[i][j][t] + bv;
        }
    }
}

// ---------------------------------------------------------------------------
// Fallback: split-K=2 GEMM, atomic f32 accumulate (used when ws too small).
// ---------------------------------------------------------------------------
__global__ __launch_bounds__(256) void gemm_bt_sk2(
    const u16* __restrict__ A, const u16* __restrict__ Bt,
    const float* __restrict__ bias, float* __restrict__ Cout,
    int M, int N, int K)
{
    __shared__ alignas(16) u16 As[3][128 * 32];
    __shared__ alignas(16) u16 Bs[3][128 * 32];
    const int tid = threadIdx.x;
    const int w = tid >> 6, lane = tid & 63;
    const int lm = lane & 15, quad = lane >> 4;
    const int wm = w >> 1, wn = w & 1;
    const int kh = blockIdx.z;
    const int Ks = K >> 1;
    const size_t m0 = (size_t)blockIdx.y * 128, n0 = (size_t)blockIdx.x * 128;

    const int bwr = swz_inv(lane);
    const int rowS = w * 16 + (bwr >> 2);
    const int colS = (bwr & 3) * 8;
    const u16* gA = A + (m0 + rowS) * K + (size_t)kh * Ks + colS;
    const u16* gB = Bt + (n0 + rowS) * K + (size_t)kh * Ks + colS;

    floatx4 acc[4][4];
    const floatx4 z = {0.f, 0.f, 0.f, 0.f};
#pragma unroll
    for (int i = 0; i < 4; ++i)
#pragma unroll
        for (int j = 0; j < 4; ++j) acc[i][j] = z;

    gemm_core(gA, gB, K, Ks >> 5, As, Bs, w, wm, wn, lm, quad, acc);

#pragma unroll
    for (int i = 0; i < 4; ++i) {
        const size_t r0 = m0 + wm * 64 + i * 16 + quad * 4;
#pragma unroll
        for (int j = 0; j < 4; ++j) {
            const size_t c = n0 + wn * 64 + j * 16 + lm;
            const float bv = (kh == 0) ? bias[c] : 0.f;
#pragma unroll
            for (int t = 0; t < 4; ++t)
                atomicAdd(&Cout[(r0 + t) * (size_t)N + c], acc[i][j][t] + bv);
        }
    }
}

// ---------------------------------------------------------------------------
// Fused QKV GEMM: A(M x 1024) @ Wqkv (1024 x 3072), Wqkvt rows: [WQ^T;WK^T;WV^T].
// Q,K written [m][1024]; V written transposed per head: Vt[((b*16+h)*64+dh)*S + s].
// ---------------------------------------------------------------------------
__global__ __launch_bounds__(256) void gemm_qkv(
    const u16* __restrict__ A, const u16* __restrict__ Bt,
    const float* __restrict__ bQ, const float* __restrict__ bK,
    const float* __restrict__ bV,
    u16* __restrict__ Qb, u16* __restrict__ Kb, u16* __restrict__ Vt)
{
    const int K = D_;
    __shared__ alignas(16) u16 As[3][128 * 32];
    __shared__ alignas(16) u16 Bs[3][128 * 32];
    const int tid = threadIdx.x;
    const int w = tid >> 6, lane = tid & 63;
    const int lm = lane & 15, quad = lane >> 4;
    const int wm = w >> 1, wn = w & 1;

    const int nwg = gridDim.x * gridDim.y;
    int bid = blockIdx.y * gridDim.x + blockIdx.x;
    if ((nwg & 7) == 0) {
        const int cpx = nwg >> 3;
        bid = (bid & 7) * cpx + (bid >> 3);
    }
    const int bx = bid % gridDim.x, by = bid / gridDim.x;
    const size_t m0 = (size_t)by * 128, n0 = (size_t)bx * 128;

    const int bwr = swz_inv(lane);
    const int rowS = w * 16 + (bwr >> 2);
    const int colS = (bwr & 3) * 8;
    const u16* gA = A + (m0 + rowS) * K + colS;
    const u16* gB = Bt + (n0 + rowS) * K + colS;

    floatx4 acc[4][4];
    const floatx4 z = {0.f, 0.f, 0.f, 0.f};
#pragma unroll
    for (int i = 0; i < 4; ++i)
#pragma unroll
        for (int j = 0; j < 4; ++j) acc[i][j] = z;

    gemm_core(gA, gB, K, K >> 5, As, Bs, w, wm, wn, lm, quad, acc);

#pragma unroll
    for (int i = 0; i < 4; ++i) {
        const size_t r0 = m0 + wm * 64 + i * 16 + quad * 4;
#pragma unroll
        for (int j = 0; j < 4; ++j) {
            const size_t c = n0 + wn * 64 + j * 16 + lm;
            const int sel = (int)(c >> 10);       // 0=Q 1=K 2=V (uniform per j)
            const int col = (int)(c & 1023);
            const float bv = sel == 0 ? bQ[col] : (sel == 1 ? bK[col] : bV[col]);
#pragma unroll
            for (int t = 0; t < 4; ++t) {
                const size_t r = r0 + t;
                const u16 v = f2bf(acc[i][j][t] + bv);
                if (sel == 0)      Qb[r * (size_t)D_ + col] = v;
                else if (sel == 1) Kb[r * (size_t)D_ + col] = v;
                else {
                    const int h = col >> 6, dh = col & 63;
                    const int bb = (int)(r >> 11), s = (int)(r & 2047);
                    Vt[((size_t)((bb * 16 + h) * 64 + dh)) * S_ + s] = v;
                }
            }
        }
    }
}

// ---------------------------------------------------------------------------
// Flash attention, S^T formulation: grid (S/64, B*H); 4 waves x 16 queries.
// exp2-domain softmax, cvt_pk bf16 packing, defer-max rescale, dbuf LDS.
// V tile XOR-swizzled (byte-col ^ 8 when row&8): kills the 2-way bank
// conflict on every PV ds_read_b64 (was ~25% of kernel cycles).
// ---------------------------------------------------------------------------
__global__ __launch_bounds__(256) void attn_kernel(
    const u16* __restrict__ Q, const u16* __restrict__ Kg,
    const u16* __restrict__ Vt, const float* __restrict__ mbias,
    u16* __restrict__ O)
{
    __shared__ alignas(16) u16 Kt[2][64 * 72];
    __shared__ alignas(16) u16 Vs[2][64 * 72];   // [dh][key], XOR-swizzled
    const int tid = threadIdx.x, w = tid >> 6, lane = tid & 63;
    const int lm = lane & 15, quad = lane >> 4;
    const int b = blockIdx.y >> 4, h = blockIdx.y & 15;
    const int q0 = blockIdx.x * 64;

    // Q B-frag: n = lane&15 -> query, k = quad*8+j -> dh
    const u16* qp = Q + ((size_t)(b * S_ + q0 + w * 16 + lm)) * D_ + h * 64;
    const short8 bq0 = *(const short8*)(qp + quad * 8);
    const short8 bq1 = *(const short8*)(qp + 32 + quad * 8);

    // staging: thread covers row tid>>2 (0..63), 16 u16 at col (tid&3)*16
    const int sRow = tid >> 2, sCol = (tid & 3) * 16;
    const int wswz = (sRow & 8) ? 4 : 0;         // u16-index XOR for V writes
    const int vswz = (lane & 8) ? 4 : 0;         // u16-index XOR for V reads
    const u16* gK = Kg + ((size_t)(b * S_ + sRow)) * D_ + h * 64 + sCol;
    const u16* gV = Vt + ((size_t)((b * 16 + h) * 64 + sRow)) * S_ + sCol;

    float mrow = -1e30f, lrow = 0.f;
    floatx4 o[4];                                // o[dhs][reg], O^T layout
    const floatx4 z = {0.f, 0.f, 0.f, 0.f};
#pragma unroll
    for (int i = 0; i < 4; ++i) o[i] = z;

    const float* bp = mbias + b * S_;
    const float SCL = 0.18033688011112042f;      // 0.125 * log2(e)

    // prologue: tile 0 into registers
    short8 rk0 = *(const short8*)(gK);
    short8 rk1 = *(const short8*)(gK + 8);
    short8 rv0 = *(const short8*)(gV);
    short8 rv1 = *(const short8*)(gV + 8);

    for (int it = 0; it < NT_; ++it) {
        u16* kb = Kt[it & 1];
        u16* vb = Vs[it & 1];
        *(short8*)&kb[sRow * 72 + sCol]     = rk0;
        *(short8*)&kb[sRow * 72 + sCol + 8] = rk1;
        {   // V write: two b64 halves per short8, addresses XOR'd by wswz
            const u64x2 v0 = __builtin_bit_cast(u64x2, rv0);
            const u64x2 v1 = __builtin_bit_cast(u64x2, rv1);
            *(u64*)&vb[sRow * 72 + ((sCol     ) ^ wswz)] = v0[0];
            *(u64*)&vb[sRow * 72 + ((sCol + 4 ) ^ wswz)] = v0[1];
            *(u64*)&vb[sRow * 72 + ((sCol + 8 ) ^ wswz)] = v1[0];
            *(u64*)&vb[sRow * 72 + ((sCol + 12) ^ wswz)] = v1[1];
        }
        __syncthreads();
        if (it + 1 < NT_) {                      // issue next tile under compute
            gK += (size_t)64 * D_; gV += 64;
            rk0 = *(const short8*)(gK);
            rk1 = *(const short8*)(gK + 8);
            rv0 = *(const short8*)(gV);
            rv1 = *(const short8*)(gV + 8);
        }

        // S^T (64 keys x 16 queries): A = K-frag, B = Q-frag
        floatx4 st[4];
        __builtin_amdgcn_s_setprio(1);
#pragma unroll
        for (int ks = 0; ks < 4; ++ks) {
            floatx4 s = z;
            const short8 ak0 = *(const short8*)&kb[(ks * 16 + lm) * 72 + quad * 8];
            const short8 ak1 = *(const short8*)&kb[(ks * 16 + lm) * 72 + 32 + quad * 8];
            s = __builtin_amdgcn_mfma_f32_16x16x32_bf16(ak0, bq0, s, 0, 0, 0);
            s = __builtin_amdgcn_mfma_f32_16x16x32_bf16(ak1, bq1, s, 0, 0, 0);
            const float4 mb4 = *(const float4*)&bp[it * 64 + ks * 16 + quad * 4];
            st[ks][0] = fmaf(s[0], SCL, mb4.x);
            st[ks][1] = fmaf(s[1], SCL, mb4.y);
            st[ks][2] = fmaf(s[2], SCL, mb4.z);
            st[ks][3] = fmaf(s[3], SCL, mb4.w);
        }
        __builtin_amdgcn_s_setprio(0);

        // tile max: balanced tree, then cross-quad (xor 16, 32)
        float m01 = fmaxf(fmaxf(st[0][0], st[0][1]), fmaxf(st[0][2], st[0][3]));
        float m11 = fmaxf(fmaxf(st[1][0], st[1][1]), fmaxf(st[1][2], st[1][3]));
        float m21 = fmaxf(fmaxf(st[2][0], st[2][1]), fmaxf(st[2][2], st[2][3]));
        float m31 = fmaxf(fmaxf(st[3][0], st[3][1]), fmaxf(st[3][2], st[3][3]));
        float tm = fmaxf(fmaxf(m01, m11), fmaxf(m21, m31));
        tm = fmaxf(tm, __shfl_xor(tm, 16));
        tm = fmaxf(tm, __shfl_xor(tm, 32));

        // defer-max: only rescale when the running max grew by > 8 (log2)
        if (!__all(tm <= mrow + 8.f)) {
            const float mn = fmaxf(mrow, tm);
            const float al = __builtin_amdgcn_exp2f(mrow - mn);
            mrow = mn;
            lrow *= al;
#pragma unroll
            for (int d = 0; d < 4; ++d) o[d] *= al;
        }

        // exp2 + tree sum
        float sks[4];
#pragma unroll
        for (int ks = 0; ks < 4; ++ks) {
#pragma unroll
            for (int r = 0; r < 4; ++r)
                st[ks][r] = __builtin_amdgcn_exp2f(st[ks][r] - mrow);
            sks[ks] = (st[ks][0] + st[ks][1]) + (st[ks][2] + st[ks][3]);
        }
        float rs = (sks[0] + sks[1]) + (sks[2] + sks[3]);
        rs += __shfl_xor(rs, 16);
        rs += __shfl_xor(rs, 32);
        lrow += rs;

        // P^T B-frags for 16x16x16: k = quad*4+j (key), n = lm (query)
        short4v pb[4];
#pragma unroll
        for (int ks = 0; ks < 4; ++ks) {
            uint2 uu;
            uu.x = cvtpk_bf16(st[ks][0], st[ks][1]);
            uu.y = cvtpk_bf16(st[ks][2], st[ks][3]);
            pb[ks] = __builtin_bit_cast(short4v, uu);
        }
        // O^T += V^T · P^T ; V^T A-frag: m=dh (lm), k=key=quad*4+j (b64 read)
        __builtin_amdgcn_s_setprio(1);
#pragma unroll
        for (int d = 0; d < 4; ++d)
#pragma unroll
            for (int ks = 0; ks < 4; ++ks) {
                const short4v av = *(const short4v*)
                    &vb[(d * 16 + lm) * 72 + ((ks * 16 + quad * 4) ^ vswz)];
                o[d] = __builtin_amdgcn_mfma_f32_16x16x16bf16_1k(av, pb[ks], o[d], 0, 0, 0);
            }
        __builtin_amdgcn_s_setprio(0);
    }
    // O^T C-layout: row=dh=quad*4+reg, col=query=lm -> 4 contiguous u16/store
    const float inv = __builtin_amdgcn_rcpf(lrow);
    u16* op = O + ((size_t)(b * S_ + q0 + w * 16 + lm)) * D_ + h * 64 + quad * 4;
#pragma unroll
    for (int d = 0; d < 4; ++d) {
        uint2 uu;
        uu.x = cvtpk_bf16(o[d][0] * inv, o[d][1] * inv);
        uu.y = cvtpk_bf16(o[d][2] * inv, o[d][3] * inv);
        *(uint2*)(op + d * 16) = uu;
    }
}

// ---------------------------------------------------------------------------
// out = LayerNorm(mainp + resid) * gamma + beta. (fallback, no partials)
// ---------------------------------------------------------------------------
template<bool MAIN_F32, bool RESID_F32, bool OUT_F32>
__global__ __launch_bounds__(256) void add_ln(
    const void* __restrict__ mainp, const void* __restrict__ resid,
    const float* __restrict__ gamma, const float* __restrict__ beta,
    void* __restrict__ out)
{
    const int row = blockIdx.x;
    const size_t base = (size_t)row * D_;
    const int t = threadIdx.x;
    const int w = t >> 6, lane = t & 63;
    float v[4];
#pragma unroll
    for (int i = 0; i < 4; ++i) {
        const int c = i * 256 + t;
        const float mv = MAIN_F32 ? ((const float*)mainp)[base + c]
                                  : bf2f(((const u16*)mainp)[base + c]);
        const float rv = RESID_F32 ? ((const float*)resid)[base + c]
                                   : bf2f(((const u16*)resid)[base + c]);
        v[i] = mv + rv;
    }
    float s = v[0] + v[1] + v[2] + v[3];
#pragma unroll
    for (int off = 32; off >= 1; off >>= 1) s += __shfl_xor(s, off);
    __shared__ float red[8];
    if (lane == 0) red[w] = s;
    __syncthreads();
    const float mean = (red[0] + red[1] + red[2] + red[3]) * (1.0f / D_);
    float q = 0.f;
#pragma unroll
    for (int i = 0; i < 4; ++i) { const float dd = v[i] - mean; q += dd * dd; }
#pragma unroll
    for (int off = 32; off >= 1; off >>= 1) q += __shfl_xor(q, off);
    if (lane == 0) red[4 + w] = q;
    __syncthreads();
    const float var = (red[4] + red[5] + red[6] + red[7]) * (1.0f / D_);
    const float rstd = rsqrtf(var + 1e-5f);
#pragma unroll
    for (int i = 0; i < 4; ++i) {
        const int c = i * 256 + t;
        const float o = (v[i] - mean) * rstd * gamma[c] + beta[c];
        if (OUT_F32) ((float*)out)[base + c] = o;
        else         ((u16*)out)[base + c] = f2bf(o);
    }
}

// ---------------------------------------------------------------------------
// out = LayerNorm(mainp + sum(Pext partials) + resid) * gamma + beta.
// ---------------------------------------------------------------------------
template<int NEXT, bool RESID_F32, bool OUT_F32>
__global__ __launch_bounds__(256) void add_ln_red(
    const float* __restrict__ mainp, const float* __restrict__ Pext,
    const void* __restrict__ resid,
    const float* __restrict__ gamma, const float* __restrict__ beta,
    void* __restrict__ out)
{
    const int row = blockIdx.x;
    const size_t base = (size_t)row * D_;
    const int t = threadIdx.x;
    const int w = t >> 6, lane = t & 63;
    float v[4];
#pragma unroll
    for (int i = 0; i < 4; ++i) {
        const int c = i * 256 + t;
        float s = mainp[base + c];
#pragma unroll
        for (int p = 0; p < NEXT; ++p)
            s += Pext[(size_t)p * ((size_t)M_ * D_) + base + c];
        s += RESID_F32 ? ((const float*)resid)[base + c]
                       : bf2f(((const u16*)resid)[base + c]);
        v[i] = s;
    }
    float s = v[0] + v[1] + v[2] + v[3];
#pragma unroll
    for (int off = 32; off >= 1; off >>= 1) s += __shfl_xor(s, off);
    __shared__ float red[8];
    if (lane == 0) red[w] = s;
    __syncthreads();
    const float mean = (red[0] + red[1] + red[2] + red[3]) * (1.0f / D_);
    float q = 0.f;
#pragma unroll
    for (int i = 0; i < 4; ++i) { const float dd = v[i] - mean; q += dd * dd; }
#pragma unroll
    for (int off = 32; off >= 1; off >>= 1) q += __shfl_xor(q, off);
    if (lane == 0) red[4 + w] = q;
    __syncthreads();
    const float var = (red[4] + red[5] + red[6] + red[7]) * (1.0f / D_);
    const float rstd = rsqrtf(var + 1e-5f);
#pragma unroll
    for (int i = 0; i < 4; ++i) {
        const int c = i * 256 + t;
        const float o = (v[i] - mean) * rstd * gamma[c] + beta[c];
        if (OUT_F32) ((float*)out)[base + c] = o;
        else         ((u16*)out)[base + c] = f2bf(o);
    }
}

// ---------------------------------------------------------------------------
extern "C" void kernel_launch(void* const* d_in, const int* in_sizes, int n_in,
                              void* d_out, int out_size, void* d_ws, size_t ws_size,
                              hipStream_t stream)
{
    const float* x   = (const float*)d_in[0];
    const int* mask  = (const int*)d_in[1];
    const float* WQ = (const float*)d_in[2];  const float* bQ = (const float*)d_in[3];
    const float* WK = (const float*)d_in[4];  const float* bK = (const float*)d_in[5];
    const float* WV = (const float*)d_in[6];  const float* bV = (const float*)d_in[7];
    const float* WY = (const float*)d_in[8];  const float* bY = (const float*)d_in[9];
    const float* ln1w = (const float*)d_in[10]; const float* ln1b = (const float*)d_in[11];
    const float* ln2w = (const float*)d_in[12]; const float* ln2b = (const float*)d_in[13];
    const float* W1 = (const float*)d_in[14]; const float* b1 = (const float*)d_in[15];
    const float* W2 = (const float*)d_in[16]; const float* b2 = (const float*)d_in[17];

    char* ws = (char*)d_ws;
    u16* xb    = (u16*)(ws + 0  * MB_);
    u16* Wqkvt = (u16*)(ws + 8  * MB_);        // 6 MB: [WQ^T; WK^T; WV^T]
    u16* WYt   = (u16*)(ws + 14 * MB_);        // 2 MB
    u16* Qb    = (u16*)(ws + 16 * MB_);
    u16* Kb    = (u16*)(ws + 24 * MB_);
    u16* Vt    = (u16*)(ws + 32 * MB_);        // [b][h][dh][s]
    u16* Yat   = (u16*)(ws + 40 * MB_);
    float* Ypf = (float*)(ws + 16 * MB_);      // 16 MB f32, after Qb/Kb dead
    u16* hbf   = (u16*)(ws + 8  * MB_);        // after Wqkvt/WYt dead
    u16* W1t   = (u16*)(ws + 0  * MB_);        // after xb dead
    u16* G     = (u16*)(ws + 16 * MB_);        // after Ypf/Vt/Yat dead
    u16* W2t   = (u16*)(ws + 0  * MB_);        // after W1t dead
    float* mb  = (float*)(ws + 48 * MB_);      // 16 KB mask bias
    float* Pext = (float*)(ws + 49 * MB_);     // split-K partial (f32)

    const size_t PART = (size_t)M_ * D_ * sizeof(float);          // 16 MB
    const bool ws1 = ws_size >= 49 * MB_ + 1 * PART;              // >= 65 MB

    const dim3 tb(32, 8);

    cvt_f32_bf16<<<(M_*D_)/1024, 256, 0, stream>>>(x, xb, M_*D_);
    mask_bias<<<(B_*S_)/256, 256, 0, stream>>>(mask, mb, B_*S_);
    transpose_cvt4<<<dim3(D_/32, D_/32, 4), tb, 0, stream>>>(WQ, WK, WV, WY, Wqkvt, WYt);

    gemm_qkv<<<dim3(3*D_/128, M_/128), 256, 0, stream>>>(xb, Wqkvt, bQ, bK, bV, Qb, Kb, Vt);

    attn_kernel<<<dim3(S_/64, B_*H_), 256, 0, stream>>>(Qb, Kb, Vt, mb, Yat);

    // ---- Y-proj (N=1024): split-K=2 partial stores ----
    if (ws1) {
        gemm_bt_skp<<<dim3(D_/128, M_/128, 2), 256, 0, stream>>>(
            Yat, WYt, bY, Ypf, Pext, M_, D_, D_);
        add_ln_red<1,true,false><<<M_, 256, 0, stream>>>(Ypf, Pext, x, ln1w, ln1b, hbf);
    } else {
        hipMemsetAsync(Ypf, 0, PART, stream);
        gemm_bt_sk2<<<dim3(D_/128, M_/128, 2), 256, 0, stream>>>(
            Yat, WYt, bY, Ypf, M_, D_, D_);
        add_ln<true,true,false><<<M_, 256, 0, stream>>>(Ypf, x, ln1w, ln1b, hbf);
    }

    transpose_cvt<<<dim3(FF_/32, D_/32), tb, 0, stream>>>(W1, W1t, D_, FF_);
    gemm_bt<true,false><<<dim3(FF_/128, M_/128), 256, 0, stream>>>(hbf, W1t, b1, G, M_, FF_, D_);

    transpose_cvt<<<dim3(D_/32, FF_/32), tb, 0, stream>>>(W2, W2t, FF_, D_);

    // ---- FF2 (N=1024, K=4096): split-K=2 partial stores ----
    if (ws1) {
        gemm_bt_skp<<<dim3(D_/128, M_/128, 2), 256, 0, stream>>>(
            G, W2t, b2, (float*)d_out, Pext, M_, D_, FF_);
        add_ln_red<1,false,true><<<M_, 256, 0, stream>>>(
            (float*)d_out, Pext, hbf, ln2w, ln2b, d_out);
    } else {
        hipMemsetAsync(d_out, 0, (size_t)M_ * D_ * 4, stream);
        gemm_bt_sk2<<<dim3(D_/128, M_/128, 2), 256, 0, stream>>>(
            G, W2t, b2, (float*)d_out, M_, D_, FF_);
        add_ln<true,false,true><<<M_, 256, 0, stream>>>(
            (float*)d_out, hbf, ln2w, ln2b, d_out);
    }
}